// Round 5
// baseline (1407.782 us; speedup 1.0000x reference)
//
#include <hip/hip_runtime.h>

// ---------------------------------------------------------------------------
// GAT 2-layer forward (N=50k, F=128, L1: H=4 x 64, L2: 1 x 64), MI355X.
// Round 5: SAME validated pipeline as R4 (all canaries silent), but output is
// written as FLOAT32 (reference's output dtype) -- R2-R4 wrote bf16 into an
// f32 buffer, which exactly reproduces the observed absmax 2.84 (> all-zeros
// 2.73). Diagnostics stripped.
// ---------------------------------------------------------------------------

static inline int cdiv(int a, int b) { return (a + b - 1) / b; }

__device__ __forceinline__ float bf2f(unsigned short u) {
  return __uint_as_float(((unsigned int)u) << 16);
}
__device__ __forceinline__ unsigned short f2bf(float f) {  // RNE
  unsigned int u = __float_as_uint(f);
  unsigned int r = (u + 0x7FFFu + ((u >> 16) & 1u)) >> 16;
  return (unsigned short)r;
}
#define NEG_INF (-__builtin_inff())

// flags[0]=1 if float tensors are bf16 (else f32); flags[1]=1 if edges int64
__global__ void detect_kernel(const unsigned short* __restrict__ xu,
                              const unsigned int* __restrict__ eu,
                              int* __restrict__ flags) {
  __shared__ int c0, c1;
  if (threadIdx.x == 0) { c0 = 0; c1 = 0; }
  __syncthreads();
  int l0 = 0, l1 = 0;
  for (int i = threadIdx.x; i < 1024; i += 256) {
    int e0 = (xu[2 * i] >> 7) & 0xFF;
    if (e0 >= 100 && e0 <= 141) l0++;
    if (eu[2 * i + 1] == 0u) l1++;
  }
  atomicAdd(&c0, l0); atomicAdd(&c1, l1);
  __syncthreads();
  if (threadIdx.x == 0) {
    flags[0] = (c0 > 512) ? 1 : 0;
    flags[1] = (c1 > 512) ? 1 : 0;
  }
}

__global__ void fill_out_kernel(float* __restrict__ out, int n, float val) {
  int t = blockIdx.x * blockDim.x + threadIdx.x;
  if (t < n) out[t] = val;
}

__global__ void canon_edges(const void* __restrict__ ei, int E, int EP, int Nn,
                            const int* __restrict__ flags,
                            int* __restrict__ srcI, int* __restrict__ dstI) {
  int t = blockIdx.x * blockDim.x + threadIdx.x;
  if (t >= EP) return;
  int s, d;
  if (t < E) {
    if (flags[1]) {
      const unsigned int* p = (const unsigned int*)ei;
      s = (int)p[2 * (size_t)t];
      d = (int)p[2 * ((size_t)E + t)];
    } else {
      const int* p = (const int*)ei;
      s = p[t]; d = p[E + t];
    }
  } else { s = t - E; d = s; }
  if ((unsigned)s >= (unsigned)Nn) s = 0;
  if ((unsigned)d >= (unsigned)Nn) d = 0;
  srcI[t] = s; dstI[t] = d;
}

__global__ void canon_bf16(const void* __restrict__ src, unsigned short* __restrict__ dst,
                           int n, const int* __restrict__ flags) {
  int t = blockIdx.x * blockDim.x + threadIdx.x;
  if (t >= n) return;
  if (flags[0]) dst[t] = ((const unsigned short*)src)[t];
  else          dst[t] = f2bf(((const float*)src)[t]);
}

__global__ void to_f32(const void* __restrict__ src, float* __restrict__ dst,
                       int n, const int* __restrict__ flags) {
  int t = blockIdx.x * blockDim.x + threadIdx.x;
  if (t >= n) return;
  dst[t] = flags[0] ? bf2f(((const unsigned short*)src)[t])
                    : ((const float*)src)[t];
}

// ---- CSR build ----
__global__ void count_deg(const int* __restrict__ dstI, int EP, int* __restrict__ deg) {
  int t = blockIdx.x * blockDim.x + threadIdx.x;
  if (t < EP) atomicAdd(&deg[dstI[t]], 1);
}

__global__ void scan1(const int* __restrict__ deg, int N,
                      int* __restrict__ incl, int* __restrict__ bsum) {
  __shared__ int s[256];
  int i = blockIdx.x * 256 + threadIdx.x;
  int v = (i < N) ? deg[i] : 0;
  s[threadIdx.x] = v;
  __syncthreads();
  for (int off = 1; off < 256; off <<= 1) {
    int add = (threadIdx.x >= off) ? s[threadIdx.x - off] : 0;
    __syncthreads();
    s[threadIdx.x] += add;
    __syncthreads();
  }
  if (i < N) incl[i] = s[threadIdx.x];
  if (threadIdx.x == 255) bsum[blockIdx.x] = s[255];
}

__global__ void scan2(int* __restrict__ bsum, int nb) {
  __shared__ int s[256];
  int t = threadIdx.x;
  int v = (t < nb) ? bsum[t] : 0;
  s[t] = v;
  __syncthreads();
  for (int off = 1; off < 256; off <<= 1) {
    int add = (t >= off) ? s[t - off] : 0;
    __syncthreads();
    s[t] += add;
    __syncthreads();
  }
  if (t < nb) bsum[t] = s[t] - v;
}

__global__ void scan3(int* __restrict__ incl, const int* __restrict__ deg,
                      const int* __restrict__ bsum, int N) {
  int i = blockIdx.x * blockDim.x + threadIdx.x;
  if (i >= N) return;
  incl[i] = incl[i] + bsum[i >> 8] - deg[i];
}

__global__ void fill_eid(const int* __restrict__ dstI, int EP,
                         const int* __restrict__ rowst, int* __restrict__ cursor,
                         int* __restrict__ eid) {
  int t = blockIdx.x * blockDim.x + threadIdx.x;
  if (t >= EP) return;
  int d = dstI[t];
  int pos = atomicAdd(&cursor[d], 1);
  eid[rowst[d] + pos] = t;
}

// Direct per-reference logits: xs/xd rows in regs, dot with att. One wave/node.
__global__ __launch_bounds__(256) void att1_direct(const void* __restrict__ X,
    const int* __restrict__ flags,
    const unsigned short* __restrict__ W1s, const unsigned short* __restrict__ W1d,
    const float* __restrict__ a1s, const float* __restrict__ a1d,
    float* __restrict__ A1, int N) {
  const int lane = threadIdx.x & 63;
  const int n = blockIdx.x * 4 + (threadIdx.x >> 6);
  if (n >= N) return;  // wave-uniform
  const int c4 = 4 * lane, h = lane >> 4;
  float sa0=0,sa1=0,sa2=0,sa3=0, da0=0,da1=0,da2=0,da3=0;
  const bool bf = flags[0] != 0;
  const unsigned short* xu = (const unsigned short*)X;
  const float* xf = (const float*)X;
  for (int k = 0; k < 128; ++k) {
    float xv = bf ? bf2f(xu[(size_t)n * 128 + k]) : xf[(size_t)n * 128 + k];
    ushort4 ws = *(const ushort4*)(W1s + k * 256 + c4);
    ushort4 wd = *(const ushort4*)(W1d + k * 256 + c4);
    sa0 += xv * bf2f(ws.x); sa1 += xv * bf2f(ws.y);
    sa2 += xv * bf2f(ws.z); sa3 += xv * bf2f(ws.w);
    da0 += xv * bf2f(wd.x); da1 += xv * bf2f(wd.y);
    da2 += xv * bf2f(wd.z); da3 += xv * bf2f(wd.w);
  }
  const int ai = h * 64 + (c4 & 63);
  float ps = sa0*a1s[ai] + sa1*a1s[ai+1] + sa2*a1s[ai+2] + sa3*a1s[ai+3];
  float pd = da0*a1d[ai] + da1*a1d[ai+1] + da2*a1d[ai+2] + da3*a1d[ai+3];
#pragma unroll
  for (int off = 1; off <= 8; off <<= 1) {
    ps += __shfl_xor(ps, off);
    pd += __shfl_xor(pd, off);
  }
  if ((lane & 15) == 0) {
    A1[(size_t)n * 8 + h] = ps;
    A1[(size_t)n * 8 + 4 + h] = pd;
  }
}

// xs1 half GEMM: C[M,128](bf16) = Xraw[M,128] @ W1s[:, coloff:coloff+128]
template<int NPW>
__global__ __launch_bounds__(256) void gemm_x(const void* __restrict__ X,
                                              const int* __restrict__ flags,
                                              const unsigned short* __restrict__ B,
                                              int coloff,
                                              unsigned short* __restrict__ C, int M) {
  const int col = threadIdx.x;
  const int n0 = blockIdx.x * (2 * NPW) + threadIdx.y * NPW;
  float acc[NPW];
  int rows[NPW];
#pragma unroll
  for (int i = 0; i < NPW; ++i) { acc[i] = 0.0f; rows[i] = min(n0 + i, M - 1); }
  const unsigned short* Bp = B + coloff + col;
  if (flags[0]) {
    const unsigned int* A32 = (const unsigned int*)X;
    for (int k2 = 0; k2 < 64; ++k2) {
      float b0 = bf2f(Bp[(2 * k2) * 256]);
      float b1 = bf2f(Bp[(2 * k2 + 1) * 256]);
#pragma unroll
      for (int i = 0; i < NPW; ++i) {
        unsigned int au = A32[(size_t)rows[i] * 64 + k2];
        acc[i] += __uint_as_float(au << 16) * b0;
        acc[i] += __uint_as_float(au & 0xFFFF0000u) * b1;
      }
    }
  } else {
    const float* Af = (const float*)X;
    for (int k = 0; k < 128; ++k) {
      float b = bf2f(Bp[k * 256]);
#pragma unroll
      for (int i = 0; i < NPW; ++i)
        acc[i] += Af[(size_t)rows[i] * 128 + k] * b;
    }
  }
#pragma unroll
  for (int i = 0; i < NPW; ++i) {
    int n = n0 + i;
    if (n < M) C[(size_t)n * 128 + col] = f2bf(acc[i]);
  }
}

// Layer-1 node pass (heads 2P,2P+1): two-pass softmax + aggregate; fused
// layer-2 GEMM partials (xs2 += h@W2s) and layer-2 logits
// (a_s2 += (h@W2s).att2s, a_d2 += (h@W2d).att2d). One wave per node.
template<int PASS>
__global__ __launch_bounds__(256) void node1_fused(
    const int* __restrict__ rowst, const int* __restrict__ deg,
    const int* __restrict__ eid, const int* __restrict__ srcI,
    const float* __restrict__ A1, const unsigned short* __restrict__ xs1h,
    const float* __restrict__ b1f,
    const unsigned short* __restrict__ W2s, const unsigned short* __restrict__ W2d,
    const float* __restrict__ a2s, const float* __restrict__ a2d,
    unsigned short* __restrict__ xs2, float* __restrict__ A2, int N) {
  __shared__ float lds_h[4][128];
  const int lane = threadIdx.x & 63;
  const int wid = threadIdx.x >> 6;
  const int nraw = blockIdx.x * 4 + wid;
  const bool valid = nraw < N;
  const int n = valid ? nraw : (N - 1);
  const int st = rowst[n], dn = deg[n];
  const float ad0 = A1[(size_t)n * 8 + 4 + 2 * PASS];
  const float ad1 = A1[(size_t)n * 8 + 4 + 2 * PASS + 1];
  // pass A: max
  float m0 = NEG_INF, m1 = NEG_INF;
  for (int j = lane; j < dn; j += 64) {
    int s = srcI[eid[st + j]];
    float v0 = A1[(size_t)s * 8 + 2 * PASS] + ad0;
    float v1 = A1[(size_t)s * 8 + 2 * PASS + 1] + ad1;
    v0 = v0 > 0.f ? v0 : 0.2f * v0;
    v1 = v1 > 0.f ? v1 : 0.2f * v1;
    m0 = fmaxf(m0, v0); m1 = fmaxf(m1, v1);
  }
#pragma unroll
  for (int off = 32; off; off >>= 1) {
    m0 = fmaxf(m0, __shfl_xor(m0, off));
    m1 = fmaxf(m1, __shfl_xor(m1, off));
  }
  // pass B: sum exp
  float l0 = 0.f, l1 = 0.f;
  for (int j = lane; j < dn; j += 64) {
    int s = srcI[eid[st + j]];
    float v0 = A1[(size_t)s * 8 + 2 * PASS] + ad0;
    float v1 = A1[(size_t)s * 8 + 2 * PASS + 1] + ad1;
    v0 = v0 > 0.f ? v0 : 0.2f * v0;
    v1 = v1 > 0.f ? v1 : 0.2f * v1;
    l0 += __expf(v0 - m0); l1 += __expf(v1 - m1);
  }
#pragma unroll
  for (int off = 32; off; off >>= 1) {
    l0 += __shfl_xor(l0, off);
    l1 += __shfl_xor(l1, off);
  }
  // pass C: weighted aggregate; lane owns local channels c, c+1
  const int c = 2 * lane;
  const int hL = lane >> 5;
  const float mh = hL ? m1 : m0;
  const float lh = hL ? l1 : l0;
  const float adh = hL ? ad1 : ad0;
  const float inv = 1.0f / lh;
  float a0 = 0.f, a1 = 0.f;
  for (int j = 0; j < dn; ++j) {
    int s = srcI[eid[st + j]];
    float v = A1[(size_t)s * 8 + 2 * PASS + hL] + adh;
    v = v > 0.f ? v : 0.2f * v;
    float alpha = __expf(v - mh) * inv;
    unsigned int u = *(const unsigned int*)(xs1h + (size_t)s * 128 + c);
    a0 += alpha * __uint_as_float(u << 16);
    a1 += alpha * __uint_as_float(u & 0xFFFF0000u);
  }
  const int gc = 128 * PASS + c;
  float h0 = a0 + b1f[gc], h1v = a1 + b1f[gc + 1];
  h0 = h0 > 0.f ? h0 : 0.f;
  h1v = h1v > 0.f ? h1v : 0.f;
  lds_h[wid][c] = h0;
  lds_h[wid][c + 1] = h1v;
  __syncthreads();
  // layer-2 partial columns (src and dst transforms), att dots
  float sum = 0.f, sumd = 0.f;
  const unsigned short* Wsp = W2s + (size_t)(128 * PASS) * 64 + lane;
  const unsigned short* Wdp = W2d + (size_t)(128 * PASS) * 64 + lane;
#pragma unroll 4
  for (int k = 0; k < 128; ++k) {
    float hk = lds_h[wid][k];
    sum  += hk * bf2f(Wsp[k * 64]);
    sumd += hk * bf2f(Wdp[k * 64]);
  }
  float ps = sum * a2s[lane], pd = sumd * a2d[lane];
#pragma unroll
  for (int off = 1; off <= 32; off <<= 1) {
    ps += __shfl_xor(ps, off);
    pd += __shfl_xor(pd, off);
  }
  if (valid) {
    size_t o = (size_t)n * 64 + lane;
    if (PASS == 0) {
      xs2[o] = f2bf(sum);
      if (lane == 0) { A2[(size_t)n * 2] = ps; A2[(size_t)n * 2 + 1] = pd; }
    } else {
      xs2[o] = f2bf(bf2f(xs2[o]) + sum);
      if (lane == 0) { A2[(size_t)n * 2] += ps; A2[(size_t)n * 2 + 1] += pd; }
    }
  }
}

// layer-2 aggregation: two-pass softmax, one wave per node. FLOAT32 output.
__global__ __launch_bounds__(256) void node2(const int* __restrict__ rowst,
    const int* __restrict__ deg, const int* __restrict__ eid,
    const int* __restrict__ srcI, const float* __restrict__ A2,
    const unsigned short* __restrict__ xs2, const float* __restrict__ b2f,
    float* __restrict__ out, int N) {
  const int lane = threadIdx.x & 63;
  const int n = blockIdx.x * 4 + (threadIdx.x >> 6);
  if (n >= N) return;  // wave-uniform
  const int st = rowst[n], dn = deg[n];
  const float ad = A2[(size_t)n * 2 + 1];
  float m = NEG_INF;
  for (int j = lane; j < dn; j += 64) {
    int s = srcI[eid[st + j]];
    float v = A2[(size_t)s * 2] + ad;
    v = v > 0.f ? v : 0.2f * v;
    m = fmaxf(m, v);
  }
#pragma unroll
  for (int off = 32; off; off >>= 1) m = fmaxf(m, __shfl_xor(m, off));
  float l = 0.f;
  for (int j = lane; j < dn; j += 64) {
    int s = srcI[eid[st + j]];
    float v = A2[(size_t)s * 2] + ad;
    v = v > 0.f ? v : 0.2f * v;
    l += __expf(v - m);
  }
#pragma unroll
  for (int off = 32; off; off >>= 1) l += __shfl_xor(l, off);
  float inv = 1.0f / l;
  float acc = 0.f;
  for (int j = 0; j < dn; ++j) {
    int s = srcI[eid[st + j]];
    float v = A2[(size_t)s * 2] + ad;
    v = v > 0.f ? v : 0.2f * v;
    acc += __expf(v - m) * inv * bf2f(xs2[(size_t)s * 64 + lane]);
  }
  out[(size_t)n * 64 + lane] = acc + b2f[lane];   // f32 write
}

extern "C" void kernel_launch(void* const* d_in, const int* in_sizes, int n_in,
                              void* d_out, int out_size, void* d_ws, size_t ws_size,
                              hipStream_t stream) {
  const int F = 128, HC1 = 256, C2 = 64;
  const int N  = in_sizes[0] / F;
  const int E  = in_sizes[1] / 2;
  const int EP = E + N;
  (void)n_in;

  char* w = (char*)d_ws;
  size_t off = 0;
  auto alloc = [&](size_t bytes) -> char* {
    char* p = w + off;
    off = (off + bytes + 255) & ~(size_t)255;
    return p;
  };
  int* flags  = (int*)alloc(256);
  int* srcI   = (int*)alloc((size_t)EP * 4);
  int* dstI   = (int*)alloc((size_t)EP * 4);       // overlaid by A1 later
  int* degcur = (int*)alloc((size_t)2 * N * 4);    // zeroed
  int* deg    = degcur;
  int* cursor = degcur + N;
  int* rowst  = (int*)alloc((size_t)N * 4);
  int* bsum   = (int*)alloc(1024);
  unsigned short* W1c  = (unsigned short*)alloc((size_t)F * HC1 * 2);
  unsigned short* W1dc = (unsigned short*)alloc((size_t)F * HC1 * 2);
  unsigned short* W2c  = (unsigned short*)alloc((size_t)HC1 * C2 * 2);
  unsigned short* W2dc = (unsigned short*)alloc((size_t)HC1 * C2 * 2);
  float* a1sf = (float*)alloc(256 * 4);
  float* a1df = (float*)alloc(256 * 4);
  float* a2sf = (float*)alloc(64 * 4);
  float* a2df = (float*)alloc(64 * 4);
  float* b1f  = (float*)alloc(256 * 4);
  float* b2f  = (float*)alloc(64 * 4);
  int*   eid  = (int*)alloc((size_t)EP * 4);
  unsigned short* xs1h = (unsigned short*)alloc((size_t)N * 128 * 2);
  unsigned short* xs2  = (unsigned short*)alloc((size_t)N * C2 * 2);
  float* A2 = (float*)alloc((size_t)N * 2 * 4);
  float* A1 = (float*)dstI;  // overlay after CSR build (1.6MB <= 1.8MB)
  const size_t need = off;   // ~26 MB

  if (ws_size < need) {  // canary: report ws MB via output
    fill_out_kernel<<<cdiv(out_size, 256), 256, 0, stream>>>(
        (float*)d_out, out_size, 131072.0f + 1024.0f * (float)(ws_size >> 20));
    return;
  }

  hipMemsetAsync(degcur, 0, (size_t)2 * N * 4, stream);
  detect_kernel<<<1, 256, 0, stream>>>((const unsigned short*)d_in[0],
                                       (const unsigned int*)d_in[1], flags);
  canon_edges<<<cdiv(EP, 256), 256, 0, stream>>>(d_in[1], E, EP, N, flags, srcI, dstI);
  canon_bf16<<<cdiv(F * HC1, 256), 256, 0, stream>>>(d_in[2], W1c, F * HC1, flags);
  canon_bf16<<<cdiv(F * HC1, 256), 256, 0, stream>>>(d_in[3], W1dc, F * HC1, flags);
  canon_bf16<<<cdiv(HC1 * C2, 256), 256, 0, stream>>>(d_in[7], W2c, HC1 * C2, flags);
  canon_bf16<<<cdiv(HC1 * C2, 256), 256, 0, stream>>>(d_in[8], W2dc, HC1 * C2, flags);
  to_f32<<<1, 256, 0, stream>>>(d_in[4], a1sf, 256, flags);
  to_f32<<<1, 256, 0, stream>>>(d_in[5], a1df, 256, flags);
  to_f32<<<1, 256, 0, stream>>>(d_in[9], a2sf, 64, flags);
  to_f32<<<1, 256, 0, stream>>>(d_in[10], a2df, 64, flags);
  to_f32<<<1, 256, 0, stream>>>(d_in[6], b1f, 256, flags);
  to_f32<<<1, 256, 0, stream>>>(d_in[11], b2f, 64, flags);

  count_deg<<<cdiv(EP, 256), 256, 0, stream>>>(dstI, EP, deg);
  const int nb = cdiv(N, 256);
  scan1<<<nb, 256, 0, stream>>>(deg, N, rowst, bsum);
  scan2<<<1, 256, 0, stream>>>(bsum, nb);
  scan3<<<nb, 256, 0, stream>>>(rowst, deg, bsum, N);
  fill_eid<<<cdiv(EP, 256), 256, 0, stream>>>(dstI, EP, rowst, cursor, eid);

  // attention logits (overwrites dstI region as A1 -- dstI dead after fill_eid)
  att1_direct<<<cdiv(N, 4), 256, 0, stream>>>(d_in[0], flags, W1c, W1dc,
                                              a1sf, a1df, A1, N);

  gemm_x<16><<<cdiv(N, 32), dim3(128, 2), 0, stream>>>(d_in[0], flags, W1c, 0, xs1h, N);
  node1_fused<0><<<cdiv(N, 4), 256, 0, stream>>>(rowst, deg, eid, srcI, A1, xs1h,
                                                 b1f, W2c, W2dc, a2sf, a2df, xs2, A2, N);
  gemm_x<16><<<cdiv(N, 32), dim3(128, 2), 0, stream>>>(d_in[0], flags, W1c, 128, xs1h, N);
  node1_fused<1><<<cdiv(N, 4), 256, 0, stream>>>(rowst, deg, eid, srcI, A1, xs1h,
                                                 b1f, W2c, W2dc, a2sf, a2df, xs2, A2, N);

  node2<<<cdiv(N, 4), 256, 0, stream>>>(rowst, deg, eid, srcI, A2, xs2, b2f,
                                        (float*)d_out, N);
}

// Round 6
// 888.241 us; speedup vs baseline: 1.5849x; 1.5849x over previous
//
#include <hip/hip_runtime.h>

// ---------------------------------------------------------------------------
// GAT 2-layer forward (N=50k, F=128, L1: H=4 x 64, L2: 1 x 64), MI355X.
// Round 6: replace att1_direct (469us brute-force, 33% of total) with fused
// attention vectors (a_s = x @ (W1s.att1s), 0.1 GF) -- algebra validated in
// R4 (identical results both ways). Add LDS-cached alpha fast path (deg<=64)
// to node1_fused/node2 serial gather loops.
// ---------------------------------------------------------------------------

static inline int cdiv(int a, int b) { return (a + b - 1) / b; }

__device__ __forceinline__ float bf2f(unsigned short u) {
  return __uint_as_float(((unsigned int)u) << 16);
}
__device__ __forceinline__ unsigned short f2bf(float f) {  // RNE
  unsigned int u = __float_as_uint(f);
  unsigned int r = (u + 0x7FFFu + ((u >> 16) & 1u)) >> 16;
  return (unsigned short)r;
}
#define NEG_INF (-__builtin_inff())

// flags[0]=1 if float tensors are bf16 (else f32); flags[1]=1 if edges int64
__global__ void detect_kernel(const unsigned short* __restrict__ xu,
                              const unsigned int* __restrict__ eu,
                              int* __restrict__ flags) {
  __shared__ int c0, c1;
  if (threadIdx.x == 0) { c0 = 0; c1 = 0; }
  __syncthreads();
  int l0 = 0, l1 = 0;
  for (int i = threadIdx.x; i < 1024; i += 256) {
    int e0 = (xu[2 * i] >> 7) & 0xFF;
    if (e0 >= 100 && e0 <= 141) l0++;
    if (eu[2 * i + 1] == 0u) l1++;
  }
  atomicAdd(&c0, l0); atomicAdd(&c1, l1);
  __syncthreads();
  if (threadIdx.x == 0) {
    flags[0] = (c0 > 512) ? 1 : 0;
    flags[1] = (c1 > 512) ? 1 : 0;
  }
}

__global__ void fill_out_kernel(float* __restrict__ out, int n, float val) {
  int t = blockIdx.x * blockDim.x + threadIdx.x;
  if (t < n) out[t] = val;
}

__global__ void canon_edges(const void* __restrict__ ei, int E, int EP, int Nn,
                            const int* __restrict__ flags,
                            int* __restrict__ srcI, int* __restrict__ dstI) {
  int t = blockIdx.x * blockDim.x + threadIdx.x;
  if (t >= EP) return;
  int s, d;
  if (t < E) {
    if (flags[1]) {
      const unsigned int* p = (const unsigned int*)ei;
      s = (int)p[2 * (size_t)t];
      d = (int)p[2 * ((size_t)E + t)];
    } else {
      const int* p = (const int*)ei;
      s = p[t]; d = p[E + t];
    }
  } else { s = t - E; d = s; }
  if ((unsigned)s >= (unsigned)Nn) s = 0;
  if ((unsigned)d >= (unsigned)Nn) d = 0;
  srcI[t] = s; dstI[t] = d;
}

__global__ void canon_bf16(const void* __restrict__ src, unsigned short* __restrict__ dst,
                           int n, const int* __restrict__ flags) {
  int t = blockIdx.x * blockDim.x + threadIdx.x;
  if (t >= n) return;
  if (flags[0]) dst[t] = ((const unsigned short*)src)[t];
  else          dst[t] = f2bf(((const float*)src)[t]);
}

__global__ void to_f32(const void* __restrict__ src, float* __restrict__ dst,
                       int n, const int* __restrict__ flags) {
  int t = blockIdx.x * blockDim.x + threadIdx.x;
  if (t >= n) return;
  dst[t] = flags[0] ? bf2f(((const unsigned short*)src)[t])
                    : ((const float*)src)[t];
}

// v[k, base+h] = sum_c W[k, h*C+c] * att[h, c]  (fused attention vector)
__global__ void make_v(const void* __restrict__ W, const void* __restrict__ att,
                       const int* __restrict__ flags, float* __restrict__ v,
                       int K, int H, int C, int stride, int base) {
  int t = blockIdx.x * blockDim.x + threadIdx.x;
  if (t >= K * H) return;
  int k = t / H, h = t - k * H;
  const int HC = H * C;
  int bf = flags[0];
  float s = 0.0f;
  for (int c = 0; c < C; ++c) {
    float wv = bf ? bf2f(((const unsigned short*)W)[k * HC + h * C + c])
                  : ((const float*)W)[k * HC + h * C + c];
    float av = bf ? bf2f(((const unsigned short*)att)[h * C + c])
                  : ((const float*)att)[h * C + c];
    s += wv * av;
  }
  v[k * stride + base + h] = s;
}

// A1[n, q] = sum_k x[n,k] * V[k*8+q]   (q: 0-3 a_s heads, 4-7 a_d heads)
__global__ void gemv_att1(const void* __restrict__ X, const int* __restrict__ flags,
                          const float* __restrict__ V, float* __restrict__ O, int M) {
  int t = blockIdx.x * blockDim.x + threadIdx.x;
  int n = t >> 3, q = t & 7;
  if (n >= M) return;
  float s = 0.0f;
  if (flags[0]) {
    const unsigned short* Xu = (const unsigned short*)X;
    for (int k = 0; k < 128; ++k) s += bf2f(Xu[(size_t)n * 128 + k]) * V[k * 8 + q];
  } else {
    const float* Xf = (const float*)X;
    for (int k = 0; k < 128; ++k) s += Xf[(size_t)n * 128 + k] * V[k * 8 + q];
  }
  O[(size_t)n * 8 + q] = s;
}

// ---- CSR build ----
__global__ void count_deg(const int* __restrict__ dstI, int EP, int* __restrict__ deg) {
  int t = blockIdx.x * blockDim.x + threadIdx.x;
  if (t < EP) atomicAdd(&deg[dstI[t]], 1);
}

__global__ void scan1(const int* __restrict__ deg, int N,
                      int* __restrict__ incl, int* __restrict__ bsum) {
  __shared__ int s[256];
  int i = blockIdx.x * 256 + threadIdx.x;
  int v = (i < N) ? deg[i] : 0;
  s[threadIdx.x] = v;
  __syncthreads();
  for (int off = 1; off < 256; off <<= 1) {
    int add = (threadIdx.x >= off) ? s[threadIdx.x - off] : 0;
    __syncthreads();
    s[threadIdx.x] += add;
    __syncthreads();
  }
  if (i < N) incl[i] = s[threadIdx.x];
  if (threadIdx.x == 255) bsum[blockIdx.x] = s[255];
}

__global__ void scan2(int* __restrict__ bsum, int nb) {
  __shared__ int s[256];
  int t = threadIdx.x;
  int v = (t < nb) ? bsum[t] : 0;
  s[t] = v;
  __syncthreads();
  for (int off = 1; off < 256; off <<= 1) {
    int add = (t >= off) ? s[t - off] : 0;
    __syncthreads();
    s[t] += add;
    __syncthreads();
  }
  if (t < nb) bsum[t] = s[t] - v;
}

__global__ void scan3(int* __restrict__ incl, const int* __restrict__ deg,
                      const int* __restrict__ bsum, int N) {
  int i = blockIdx.x * blockDim.x + threadIdx.x;
  if (i >= N) return;
  incl[i] = incl[i] + bsum[i >> 8] - deg[i];
}

__global__ void fill_eid(const int* __restrict__ dstI, int EP,
                         const int* __restrict__ rowst, int* __restrict__ cursor,
                         int* __restrict__ eid) {
  int t = blockIdx.x * blockDim.x + threadIdx.x;
  if (t >= EP) return;
  int d = dstI[t];
  int pos = atomicAdd(&cursor[d], 1);
  eid[rowst[d] + pos] = t;
}

// xs1 half GEMM: C[M,128](bf16) = Xraw[M,128] @ W1s[:, coloff:coloff+128]
template<int NPW>
__global__ __launch_bounds__(256) void gemm_x(const void* __restrict__ X,
                                              const int* __restrict__ flags,
                                              const unsigned short* __restrict__ B,
                                              int coloff,
                                              unsigned short* __restrict__ C, int M) {
  const int col = threadIdx.x;
  const int n0 = blockIdx.x * (2 * NPW) + threadIdx.y * NPW;
  float acc[NPW];
  int rows[NPW];
#pragma unroll
  for (int i = 0; i < NPW; ++i) { acc[i] = 0.0f; rows[i] = min(n0 + i, M - 1); }
  const unsigned short* Bp = B + coloff + col;
  if (flags[0]) {
    const unsigned int* A32 = (const unsigned int*)X;
    for (int k2 = 0; k2 < 64; ++k2) {
      float b0 = bf2f(Bp[(2 * k2) * 256]);
      float b1 = bf2f(Bp[(2 * k2 + 1) * 256]);
#pragma unroll
      for (int i = 0; i < NPW; ++i) {
        unsigned int au = A32[(size_t)rows[i] * 64 + k2];
        acc[i] += __uint_as_float(au << 16) * b0;
        acc[i] += __uint_as_float(au & 0xFFFF0000u) * b1;
      }
    }
  } else {
    const float* Af = (const float*)X;
    for (int k = 0; k < 128; ++k) {
      float b = bf2f(Bp[k * 256]);
#pragma unroll
      for (int i = 0; i < NPW; ++i)
        acc[i] += Af[(size_t)rows[i] * 128 + k] * b;
    }
  }
#pragma unroll
  for (int i = 0; i < NPW; ++i) {
    int n = n0 + i;
    if (n < M) C[(size_t)n * 128 + col] = f2bf(acc[i]);
  }
}

// Layer-1 node pass (heads 2P,2P+1) + fused layer-2 partials. One wave/node.
template<int PASS>
__global__ __launch_bounds__(256) void node1_fused(
    const int* __restrict__ rowst, const int* __restrict__ deg,
    const int* __restrict__ eid, const int* __restrict__ srcI,
    const float* __restrict__ A1, const unsigned short* __restrict__ xs1h,
    const float* __restrict__ b1f,
    const unsigned short* __restrict__ W2s, const unsigned short* __restrict__ W2d,
    const float* __restrict__ a2s, const float* __restrict__ a2d,
    unsigned short* __restrict__ xs2, float* __restrict__ A2, int N) {
  __shared__ float lds_h[4][128];
  __shared__ int   s_sh[4][64];
  __shared__ float al_sh[4][64][2];
  const int lane = threadIdx.x & 63;
  const int wid = threadIdx.x >> 6;
  const int nraw = blockIdx.x * 4 + wid;
  const bool valid = nraw < N;
  const int n = valid ? nraw : (N - 1);
  const int st = rowst[n], dn = deg[n];
  const float ad0 = A1[(size_t)n * 8 + 4 + 2 * PASS];
  const float ad1 = A1[(size_t)n * 8 + 4 + 2 * PASS + 1];
  const int c = 2 * lane;
  const int hL = lane >> 5;
  float a0 = 0.f, a1 = 0.f;

  if (dn <= 64) {
    // ---- fast path: one edge per lane, alphas cached in per-wave LDS ----
    int s = 0; float v0 = NEG_INF, v1 = NEG_INF;
    if (lane < dn) {
      s = srcI[eid[st + lane]];
      v0 = A1[(size_t)s * 8 + 2 * PASS] + ad0;
      v1 = A1[(size_t)s * 8 + 2 * PASS + 1] + ad1;
      v0 = v0 > 0.f ? v0 : 0.2f * v0;
      v1 = v1 > 0.f ? v1 : 0.2f * v1;
    }
    float m0 = v0, m1 = v1;
#pragma unroll
    for (int off = 32; off; off >>= 1) {
      m0 = fmaxf(m0, __shfl_xor(m0, off));
      m1 = fmaxf(m1, __shfl_xor(m1, off));
    }
    float e0 = (lane < dn) ? __expf(v0 - m0) : 0.f;
    float e1 = (lane < dn) ? __expf(v1 - m1) : 0.f;
    float l0 = e0, l1 = e1;
#pragma unroll
    for (int off = 32; off; off >>= 1) {
      l0 += __shfl_xor(l0, off);
      l1 += __shfl_xor(l1, off);
    }
    if (lane < dn) {
      s_sh[wid][lane] = s;
      al_sh[wid][lane][0] = e0 / l0;
      al_sh[wid][lane][1] = e1 / l1;
    }
    for (int j = 0; j < dn; ++j) {
      int sj = s_sh[wid][j];
      float alpha = al_sh[wid][j][hL];
      unsigned int u = *(const unsigned int*)(xs1h + (size_t)sj * 128 + c);
      a0 += alpha * __uint_as_float(u << 16);
      a1 += alpha * __uint_as_float(u & 0xFFFF0000u);
    }
  } else {
    // ---- fallback: strided two-pass softmax ----
    float m0 = NEG_INF, m1 = NEG_INF;
    for (int j = lane; j < dn; j += 64) {
      int s = srcI[eid[st + j]];
      float v0 = A1[(size_t)s * 8 + 2 * PASS] + ad0;
      float v1 = A1[(size_t)s * 8 + 2 * PASS + 1] + ad1;
      v0 = v0 > 0.f ? v0 : 0.2f * v0;
      v1 = v1 > 0.f ? v1 : 0.2f * v1;
      m0 = fmaxf(m0, v0); m1 = fmaxf(m1, v1);
    }
#pragma unroll
    for (int off = 32; off; off >>= 1) {
      m0 = fmaxf(m0, __shfl_xor(m0, off));
      m1 = fmaxf(m1, __shfl_xor(m1, off));
    }
    float l0 = 0.f, l1 = 0.f;
    for (int j = lane; j < dn; j += 64) {
      int s = srcI[eid[st + j]];
      float v0 = A1[(size_t)s * 8 + 2 * PASS] + ad0;
      float v1 = A1[(size_t)s * 8 + 2 * PASS + 1] + ad1;
      v0 = v0 > 0.f ? v0 : 0.2f * v0;
      v1 = v1 > 0.f ? v1 : 0.2f * v1;
      l0 += __expf(v0 - m0); l1 += __expf(v1 - m1);
    }
#pragma unroll
    for (int off = 32; off; off >>= 1) {
      l0 += __shfl_xor(l0, off);
      l1 += __shfl_xor(l1, off);
    }
    const float mh = hL ? m1 : m0;
    const float lh = hL ? l1 : l0;
    const float adh = hL ? ad1 : ad0;
    const float inv = 1.0f / lh;
    for (int j = 0; j < dn; ++j) {
      int s = srcI[eid[st + j]];
      float v = A1[(size_t)s * 8 + 2 * PASS + hL] + adh;
      v = v > 0.f ? v : 0.2f * v;
      float alpha = __expf(v - mh) * inv;
      unsigned int u = *(const unsigned int*)(xs1h + (size_t)s * 128 + c);
      a0 += alpha * __uint_as_float(u << 16);
      a1 += alpha * __uint_as_float(u & 0xFFFF0000u);
    }
  }

  const int gc = 128 * PASS + c;
  float h0 = a0 + b1f[gc], h1v = a1 + b1f[gc + 1];
  h0 = h0 > 0.f ? h0 : 0.f;
  h1v = h1v > 0.f ? h1v : 0.f;
  lds_h[wid][c] = h0;
  lds_h[wid][c + 1] = h1v;
  __syncthreads();
  // layer-2 partial columns (src and dst transforms), att dots
  float sum = 0.f, sumd = 0.f;
  const unsigned short* Wsp = W2s + (size_t)(128 * PASS) * 64 + lane;
  const unsigned short* Wdp = W2d + (size_t)(128 * PASS) * 64 + lane;
#pragma unroll 4
  for (int k = 0; k < 128; ++k) {
    float hk = lds_h[wid][k];
    sum  += hk * bf2f(Wsp[k * 64]);
    sumd += hk * bf2f(Wdp[k * 64]);
  }
  float ps = sum * a2s[lane], pd = sumd * a2d[lane];
#pragma unroll
  for (int off = 1; off <= 32; off <<= 1) {
    ps += __shfl_xor(ps, off);
    pd += __shfl_xor(pd, off);
  }
  if (valid) {
    size_t o = (size_t)n * 64 + lane;
    if (PASS == 0) {
      xs2[o] = f2bf(sum);
      if (lane == 0) { A2[(size_t)n * 2] = ps; A2[(size_t)n * 2 + 1] = pd; }
    } else {
      xs2[o] = f2bf(bf2f(xs2[o]) + sum);
      if (lane == 0) { A2[(size_t)n * 2] += ps; A2[(size_t)n * 2 + 1] += pd; }
    }
  }
}

// layer-2 aggregation, one wave per node. FLOAT32 output.
__global__ __launch_bounds__(256) void node2(const int* __restrict__ rowst,
    const int* __restrict__ deg, const int* __restrict__ eid,
    const int* __restrict__ srcI, const float* __restrict__ A2,
    const unsigned short* __restrict__ xs2, const float* __restrict__ b2f,
    float* __restrict__ out, int N) {
  __shared__ int   s_sh[4][64];
  __shared__ float al_sh[4][64];
  const int lane = threadIdx.x & 63;
  const int wid = threadIdx.x >> 6;
  const int n = blockIdx.x * 4 + wid;
  if (n >= N) return;  // wave-uniform, no block barriers used
  const int st = rowst[n], dn = deg[n];
  const float ad = A2[(size_t)n * 2 + 1];
  float acc = 0.f;
  if (dn <= 64) {
    int s = 0; float v = NEG_INF;
    if (lane < dn) {
      s = srcI[eid[st + lane]];
      v = A2[(size_t)s * 2] + ad;
      v = v > 0.f ? v : 0.2f * v;
    }
    float m = v;
#pragma unroll
    for (int off = 32; off; off >>= 1) m = fmaxf(m, __shfl_xor(m, off));
    float e = (lane < dn) ? __expf(v - m) : 0.f;
    float l = e;
#pragma unroll
    for (int off = 32; off; off >>= 1) l += __shfl_xor(l, off);
    if (lane < dn) { s_sh[wid][lane] = s; al_sh[wid][lane] = e / l; }
    for (int j = 0; j < dn; ++j) {
      int sj = s_sh[wid][j];
      acc += al_sh[wid][j] * bf2f(xs2[(size_t)sj * 64 + lane]);
    }
  } else {
    float m = NEG_INF;
    for (int j = lane; j < dn; j += 64) {
      int s = srcI[eid[st + j]];
      float v = A2[(size_t)s * 2] + ad;
      v = v > 0.f ? v : 0.2f * v;
      m = fmaxf(m, v);
    }
#pragma unroll
    for (int off = 32; off; off >>= 1) m = fmaxf(m, __shfl_xor(m, off));
    float l = 0.f;
    for (int j = lane; j < dn; j += 64) {
      int s = srcI[eid[st + j]];
      float v = A2[(size_t)s * 2] + ad;
      v = v > 0.f ? v : 0.2f * v;
      l += __expf(v - m);
    }
#pragma unroll
    for (int off = 32; off; off >>= 1) l += __shfl_xor(l, off);
    float inv = 1.0f / l;
    for (int j = 0; j < dn; ++j) {
      int s = srcI[eid[st + j]];
      float v = A2[(size_t)s * 2] + ad;
      v = v > 0.f ? v : 0.2f * v;
      acc += __expf(v - m) * inv * bf2f(xs2[(size_t)s * 64 + lane]);
    }
  }
  out[(size_t)n * 64 + lane] = acc + b2f[lane];
}

extern "C" void kernel_launch(void* const* d_in, const int* in_sizes, int n_in,
                              void* d_out, int out_size, void* d_ws, size_t ws_size,
                              hipStream_t stream) {
  const int F = 128, H1 = 4, C1 = 64, HC1 = 256, C2 = 64;
  const int N  = in_sizes[0] / F;
  const int E  = in_sizes[1] / 2;
  const int EP = E + N;
  (void)n_in;

  char* w = (char*)d_ws;
  size_t off = 0;
  auto alloc = [&](size_t bytes) -> char* {
    char* p = w + off;
    off = (off + bytes + 255) & ~(size_t)255;
    return p;
  };
  int* flags  = (int*)alloc(256);
  int* srcI   = (int*)alloc((size_t)EP * 4);
  int* dstI   = (int*)alloc((size_t)EP * 4);       // overlaid by A1 later
  int* degcur = (int*)alloc((size_t)2 * N * 4);    // zeroed
  int* deg    = degcur;
  int* cursor = degcur + N;
  int* rowst  = (int*)alloc((size_t)N * 4);
  int* bsum   = (int*)alloc(1024);
  unsigned short* W1c  = (unsigned short*)alloc((size_t)F * HC1 * 2);
  unsigned short* W2c  = (unsigned short*)alloc((size_t)HC1 * C2 * 2);
  unsigned short* W2dc = (unsigned short*)alloc((size_t)HC1 * C2 * 2);
  float* v1   = (float*)alloc((size_t)F * 8 * 4);
  float* a2sf = (float*)alloc(64 * 4);
  float* a2df = (float*)alloc(64 * 4);
  float* b1f  = (float*)alloc(256 * 4);
  float* b2f  = (float*)alloc(64 * 4);
  int*   eid  = (int*)alloc((size_t)EP * 4);
  unsigned short* xs1h = (unsigned short*)alloc((size_t)N * 128 * 2);
  unsigned short* xs2  = (unsigned short*)alloc((size_t)N * C2 * 2);
  float* A2 = (float*)alloc((size_t)N * 2 * 4);
  float* A1 = (float*)dstI;  // overlay after CSR build (1.6MB <= 1.8MB)
  const size_t need = off;   // ~25.5 MB

  if (ws_size < need) {  // canary: report ws MB via output
    fill_out_kernel<<<cdiv(out_size, 256), 256, 0, stream>>>(
        (float*)d_out, out_size, 131072.0f + 1024.0f * (float)(ws_size >> 20));
    return;
  }

  hipMemsetAsync(degcur, 0, (size_t)2 * N * 4, stream);
  detect_kernel<<<1, 256, 0, stream>>>((const unsigned short*)d_in[0],
                                       (const unsigned int*)d_in[1], flags);
  canon_edges<<<cdiv(EP, 256), 256, 0, stream>>>(d_in[1], E, EP, N, flags, srcI, dstI);
  canon_bf16<<<cdiv(F * HC1, 256), 256, 0, stream>>>(d_in[2], W1c, F * HC1, flags);
  canon_bf16<<<cdiv(HC1 * C2, 256), 256, 0, stream>>>(d_in[7], W2c, HC1 * C2, flags);
  canon_bf16<<<cdiv(HC1 * C2, 256), 256, 0, stream>>>(d_in[8], W2dc, HC1 * C2, flags);
  to_f32<<<1, 256, 0, stream>>>(d_in[9], a2sf, 64, flags);
  to_f32<<<1, 256, 0, stream>>>(d_in[10], a2df, 64, flags);
  to_f32<<<1, 256, 0, stream>>>(d_in[6], b1f, 256, flags);
  to_f32<<<1, 256, 0, stream>>>(d_in[11], b2f, 64, flags);
  make_v<<<cdiv(F * H1, 256), 256, 0, stream>>>(d_in[2], d_in[4], flags, v1, F, H1, C1, 8, 0);
  make_v<<<cdiv(F * H1, 256), 256, 0, stream>>>(d_in[3], d_in[5], flags, v1, F, H1, C1, 8, 4);

  count_deg<<<cdiv(EP, 256), 256, 0, stream>>>(dstI, EP, deg);
  const int nb = cdiv(N, 256);
  scan1<<<nb, 256, 0, stream>>>(deg, N, rowst, bsum);
  scan2<<<1, 256, 0, stream>>>(bsum, nb);
  scan3<<<nb, 256, 0, stream>>>(rowst, deg, bsum, N);
  fill_eid<<<cdiv(EP, 256), 256, 0, stream>>>(dstI, EP, rowst, cursor, eid);

  // attention logits via fused vectors (dstI dead -> A1 overlays it)
  gemv_att1<<<cdiv(N * 8, 256), 256, 0, stream>>>(d_in[0], flags, v1, A1, N);

  gemm_x<16><<<cdiv(N, 32), dim3(128, 2), 0, stream>>>(d_in[0], flags, W1c, 0, xs1h, N);
  node1_fused<0><<<cdiv(N, 4), 256, 0, stream>>>(rowst, deg, eid, srcI, A1, xs1h,
                                                 b1f, W2c, W2dc, a2sf, a2df, xs2, A2, N);
  gemm_x<16><<<cdiv(N, 32), dim3(128, 2), 0, stream>>>(d_in[0], flags, W1c, 128, xs1h, N);
  node1_fused<1><<<cdiv(N, 4), 256, 0, stream>>>(rowst, deg, eid, srcI, A1, xs1h,
                                                 b1f, W2c, W2dc, a2sf, a2df, xs2, A2, N);

  node2<<<cdiv(N, 4), 256, 0, stream>>>(rowst, deg, eid, srcI, A2, xs2, b2f,
                                        (float*)d_out, N);
}

// Round 7
// 513.057 us; speedup vs baseline: 2.7439x; 1.7313x over previous
//
#include <hip/hip_runtime.h>

// ---------------------------------------------------------------------------
// GAT 2-layer forward (N=50k, F=128, L1: H=4 x 64, L2: 1 x 64), MI355X.
// Round 7: MFMA-based x@W1 GEMM (was 2x218us scalar-FMA = 49% of runtime);
// A1 logits fused into pass-0 as a 9th col-tile (kills gemv_att1); node1
// epilogue: W2d dot replaced by fused v2s/v2d vectors, W2s read via
// transposed layout with dwordx4 loads.
// ---------------------------------------------------------------------------

static inline int cdiv(int a, int b) { return (a + b - 1) / b; }

typedef __attribute__((ext_vector_type(8))) short short8;
typedef __attribute__((ext_vector_type(4))) float floatx4;

__device__ __forceinline__ float bf2f(unsigned short u) {
  return __uint_as_float(((unsigned int)u) << 16);
}
__device__ __forceinline__ unsigned short f2bf(float f) {  // RNE
  unsigned int u = __float_as_uint(f);
  unsigned int r = (u + 0x7FFFu + ((u >> 16) & 1u)) >> 16;
  return (unsigned short)r;
}
#define NEG_INF (-__builtin_inff())

// flags[0]=1 if float tensors are bf16 (else f32); flags[1]=1 if edges int64
__global__ void detect_kernel(const unsigned short* __restrict__ xu,
                              const unsigned int* __restrict__ eu,
                              int* __restrict__ flags) {
  __shared__ int c0, c1;
  if (threadIdx.x == 0) { c0 = 0; c1 = 0; }
  __syncthreads();
  int l0 = 0, l1 = 0;
  for (int i = threadIdx.x; i < 1024; i += 256) {
    int e0 = (xu[2 * i] >> 7) & 0xFF;
    if (e0 >= 100 && e0 <= 141) l0++;
    if (eu[2 * i + 1] == 0u) l1++;
  }
  atomicAdd(&c0, l0); atomicAdd(&c1, l1);
  __syncthreads();
  if (threadIdx.x == 0) {
    flags[0] = (c0 > 512) ? 1 : 0;
    flags[1] = (c1 > 512) ? 1 : 0;
  }
}

__global__ void fill_out_kernel(float* __restrict__ out, int n, float val) {
  int t = blockIdx.x * blockDim.x + threadIdx.x;
  if (t < n) out[t] = val;
}

__global__ void canon_edges(const void* __restrict__ ei, int E, int EP, int Nn,
                            const int* __restrict__ flags,
                            int* __restrict__ srcI, int* __restrict__ dstI) {
  int t = blockIdx.x * blockDim.x + threadIdx.x;
  if (t >= EP) return;
  int s, d;
  if (t < E) {
    if (flags[1]) {
      const unsigned int* p = (const unsigned int*)ei;
      s = (int)p[2 * (size_t)t];
      d = (int)p[2 * ((size_t)E + t)];
    } else {
      const int* p = (const int*)ei;
      s = p[t]; d = p[E + t];
    }
  } else { s = t - E; d = s; }
  if ((unsigned)s >= (unsigned)Nn) s = 0;
  if ((unsigned)d >= (unsigned)Nn) d = 0;
  srcI[t] = s; dstI[t] = d;
}

__global__ void canon_bf16(const void* __restrict__ src, unsigned short* __restrict__ dst,
                           int n, const int* __restrict__ flags) {
  int t = blockIdx.x * blockDim.x + threadIdx.x;
  if (t >= n) return;
  if (flags[0]) dst[t] = ((const unsigned short*)src)[t];
  else          dst[t] = f2bf(((const float*)src)[t]);
}

__global__ void to_f32(const void* __restrict__ src, float* __restrict__ dst,
                       int n, const int* __restrict__ flags) {
  int t = blockIdx.x * blockDim.x + threadIdx.x;
  if (t >= n) return;
  dst[t] = flags[0] ? bf2f(((const unsigned short*)src)[t])
                    : ((const float*)src)[t];
}

// v[k, base+h] = sum_c W[k, h*C+c] * att[h, c]  (fused attention vector)
__global__ void make_v(const void* __restrict__ W, const void* __restrict__ att,
                       const int* __restrict__ flags, float* __restrict__ v,
                       int K, int H, int C, int stride, int base) {
  int t = blockIdx.x * blockDim.x + threadIdx.x;
  if (t >= K * H) return;
  int k = t / H, h = t - k * H;
  const int HC = H * C;
  int bf = flags[0];
  float s = 0.0f;
  for (int c = 0; c < C; ++c) {
    float wv = bf ? bf2f(((const unsigned short*)W)[k * HC + h * C + c])
                  : ((const float*)W)[k * HC + h * C + c];
    float av = bf ? bf2f(((const unsigned short*)att)[h * C + c])
                  : ((const float*)att)[h * C + c];
    s += wv * av;
  }
  v[k * stride + base + h] = s;
}

// W1ext[k*16 + q] = bf16(v1[k*8 + q])  (cols 8..15 pre-zeroed by memset)
__global__ void v1_to_bf16(const float* __restrict__ v1,
                           unsigned short* __restrict__ W1ext) {
  int t = blockIdx.x * blockDim.x + threadIdx.x;
  if (t >= 1024) return;
  int k = t >> 3, q = t & 7;
  W1ext[k * 16 + q] = f2bf(v1[t]);
}

// W2sT[col*256 + k] = W2s[k*64 + col]
__global__ void transpose_w2(const void* __restrict__ W2, const int* __restrict__ flags,
                             unsigned short* __restrict__ W2sT) {
  int t = blockIdx.x * blockDim.x + threadIdx.x;
  if (t >= 256 * 64) return;
  int k = t >> 6, col = t & 63;
  unsigned short v = flags[0] ? ((const unsigned short*)W2)[t]
                              : f2bf(((const float*)W2)[t]);
  W2sT[col * 256 + k] = v;
}

// ---- CSR build ----
__global__ void count_deg(const int* __restrict__ dstI, int EP, int* __restrict__ deg) {
  int t = blockIdx.x * blockDim.x + threadIdx.x;
  if (t < EP) atomicAdd(&deg[dstI[t]], 1);
}

__global__ void scan1(const int* __restrict__ deg, int N,
                      int* __restrict__ incl, int* __restrict__ bsum) {
  __shared__ int s[256];
  int i = blockIdx.x * 256 + threadIdx.x;
  int v = (i < N) ? deg[i] : 0;
  s[threadIdx.x] = v;
  __syncthreads();
  for (int off = 1; off < 256; off <<= 1) {
    int add = (threadIdx.x >= off) ? s[threadIdx.x - off] : 0;
    __syncthreads();
    s[threadIdx.x] += add;
    __syncthreads();
  }
  if (i < N) incl[i] = s[threadIdx.x];
  if (threadIdx.x == 255) bsum[blockIdx.x] = s[255];
}

__global__ void scan2(int* __restrict__ bsum, int nb) {
  __shared__ int s[256];
  int t = threadIdx.x;
  int v = (t < nb) ? bsum[t] : 0;
  s[t] = v;
  __syncthreads();
  for (int off = 1; off < 256; off <<= 1) {
    int add = (t >= off) ? s[t - off] : 0;
    __syncthreads();
    s[t] += add;
    __syncthreads();
  }
  if (t < nb) bsum[t] = s[t] - v;
}

__global__ void scan3(int* __restrict__ incl, const int* __restrict__ deg,
                      const int* __restrict__ bsum, int N) {
  int i = blockIdx.x * blockDim.x + threadIdx.x;
  if (i >= N) return;
  incl[i] = incl[i] + bsum[i >> 8] - deg[i];
}

__global__ void fill_eid(const int* __restrict__ dstI, int EP,
                         const int* __restrict__ rowst, int* __restrict__ cursor,
                         int* __restrict__ eid) {
  int t = blockIdx.x * blockDim.x + threadIdx.x;
  if (t >= EP) return;
  int d = dstI[t];
  int pos = atomicAdd(&cursor[d], 1);
  eid[rowst[d] + pos] = t;
}

// ---- MFMA GEMM: xs1 half = x[M,128] @ W1[:, coloff:coloff+128]; pass0 also
// computes A1 = x @ v1 as a 9th col-tile (cols 128..135 of staged B).
// Block = 256 thr (4 waves); each wave does 16 rows; block does 64 rows.
// B staged transposed in LDS: Wlds[col][k], row padded to 136 bf16.
template<int NCT, int WITH_A1>
__global__ __launch_bounds__(256) void gemm_mfma(
    const void* __restrict__ X, const int* __restrict__ flags,
    const unsigned short* __restrict__ W1c, int coloff,
    const unsigned short* __restrict__ W1ext,
    unsigned short* __restrict__ C, float* __restrict__ A1, int M) {
  __shared__ unsigned short Wlds[NCT * 16 * 136];
  const int t = threadIdx.x;
  const int TC = NCT * 16;
  // ---- stage B transposed: thread t (< TC) owns column t ----
  if (t < TC) {
    for (int k0 = 0; k0 < 128; k0 += 4) {
      unsigned int u0, u1;
      if (t < 128) {
        const unsigned short* p = W1c + (size_t)k0 * 256 + coloff + t;
        u0 = (unsigned int)p[0] | ((unsigned int)p[256] << 16);
        u1 = (unsigned int)p[512] | ((unsigned int)p[768] << 16);
      } else {
        const unsigned short* p = W1ext + (size_t)k0 * 16 + (t - 128);
        u0 = (unsigned int)p[0] | ((unsigned int)p[16] << 16);
        u1 = (unsigned int)p[32] | ((unsigned int)p[48] << 16);
      }
      *(uint2*)&Wlds[t * 136 + k0] = make_uint2(u0, u1);
    }
  }
  // ---- A fragments: A[m = lane&15][k = quad*8 + j] ----
  const int lane = t & 63, wid = t >> 6;
  const int quad = lane >> 4, m16 = lane & 15;
  const int r0 = blockIdx.x * 64 + wid * 16;
  const int arow = min(r0 + m16, M - 1);
  short8 af[4];
  if (flags[0]) {
    const uint4* Xr = (const uint4*)((const unsigned int*)X + (size_t)arow * 64);
#pragma unroll
    for (int ks = 0; ks < 4; ++ks)
      af[ks] = __builtin_bit_cast(short8, Xr[ks * 4 + quad]);
  } else {
    const float* Xr = (const float*)X + (size_t)arow * 128;
#pragma unroll
    for (int ks = 0; ks < 4; ++ks) {
      short8 v;
#pragma unroll
      for (int j = 0; j < 8; ++j) v[j] = (short)f2bf(Xr[ks * 32 + quad * 8 + j]);
      af[ks] = v;
    }
  }
  __syncthreads();
  // ---- col-tile loop ----
  for (int ct = 0; ct < NCT; ++ct) {
    floatx4 acc = {0.f, 0.f, 0.f, 0.f};
    const unsigned short* wl = &Wlds[(ct * 16 + m16) * 136];
#pragma unroll
    for (int ks = 0; ks < 4; ++ks) {
      short8 bf = *(const short8*)(wl + ks * 32 + quad * 8);
      acc = __builtin_amdgcn_mfma_f32_16x16x32_bf16(af[ks], bf, acc, 0, 0, 0);
    }
    // C/D: col = lane&15, row = quad*4 + reg   [verified m89]
    if (WITH_A1 && ct == NCT - 1) {
      if (m16 < 8) {
#pragma unroll
        for (int r = 0; r < 4; ++r) {
          int row = r0 + quad * 4 + r;
          if (row < M) A1[(size_t)row * 8 + m16] = acc[r];
        }
      }
    } else {
#pragma unroll
      for (int r = 0; r < 4; ++r) {
        int row = r0 + quad * 4 + r;
        if (row < M) C[(size_t)row * 128 + ct * 16 + m16] = f2bf(acc[r]);
      }
    }
  }
}

// Layer-1 node pass (heads 2P,2P+1) + fused layer-2 partials. One wave/node.
template<int PASS>
__global__ __launch_bounds__(256) void node1_fused(
    const int* __restrict__ rowst, const int* __restrict__ deg,
    const int* __restrict__ eid, const int* __restrict__ srcI,
    const float* __restrict__ A1, const unsigned short* __restrict__ xs1h,
    const float* __restrict__ b1f, const unsigned short* __restrict__ W2sT,
    const float* __restrict__ v2s, const float* __restrict__ v2d,
    unsigned short* __restrict__ xs2, float* __restrict__ A2, int N) {
  __shared__ float lds_h[4][128];
  __shared__ int   s_sh[4][64];
  __shared__ float al_sh[4][64][2];
  const int lane = threadIdx.x & 63;
  const int wid = threadIdx.x >> 6;
  const int nraw = blockIdx.x * 4 + wid;
  const bool valid = nraw < N;
  const int n = valid ? nraw : (N - 1);
  const int st = rowst[n], dn = deg[n];
  const float ad0 = A1[(size_t)n * 8 + 4 + 2 * PASS];
  const float ad1 = A1[(size_t)n * 8 + 4 + 2 * PASS + 1];
  const int c = 2 * lane;
  const int hL = lane >> 5;
  float a0 = 0.f, a1 = 0.f;

  if (dn <= 64) {
    int s = 0; float v0 = NEG_INF, v1v = NEG_INF;
    if (lane < dn) {
      s = srcI[eid[st + lane]];
      v0 = A1[(size_t)s * 8 + 2 * PASS] + ad0;
      v1v = A1[(size_t)s * 8 + 2 * PASS + 1] + ad1;
      v0 = v0 > 0.f ? v0 : 0.2f * v0;
      v1v = v1v > 0.f ? v1v : 0.2f * v1v;
    }
    float m0 = v0, m1 = v1v;
#pragma unroll
    for (int off = 32; off; off >>= 1) {
      m0 = fmaxf(m0, __shfl_xor(m0, off));
      m1 = fmaxf(m1, __shfl_xor(m1, off));
    }
    float e0 = (lane < dn) ? __expf(v0 - m0) : 0.f;
    float e1 = (lane < dn) ? __expf(v1v - m1) : 0.f;
    float l0 = e0, l1 = e1;
#pragma unroll
    for (int off = 32; off; off >>= 1) {
      l0 += __shfl_xor(l0, off);
      l1 += __shfl_xor(l1, off);
    }
    if (lane < dn) {
      s_sh[wid][lane] = s;
      al_sh[wid][lane][0] = e0 / l0;
      al_sh[wid][lane][1] = e1 / l1;
    }
    for (int j = 0; j < dn; ++j) {
      int sj = s_sh[wid][j];
      float alpha = al_sh[wid][j][hL];
      unsigned int u = *(const unsigned int*)(xs1h + (size_t)sj * 128 + c);
      a0 += alpha * __uint_as_float(u << 16);
      a1 += alpha * __uint_as_float(u & 0xFFFF0000u);
    }
  } else {
    float m0 = NEG_INF, m1 = NEG_INF;
    for (int j = lane; j < dn; j += 64) {
      int s = srcI[eid[st + j]];
      float v0 = A1[(size_t)s * 8 + 2 * PASS] + ad0;
      float v1v = A1[(size_t)s * 8 + 2 * PASS + 1] + ad1;
      v0 = v0 > 0.f ? v0 : 0.2f * v0;
      v1v = v1v > 0.f ? v1v : 0.2f * v1v;
      m0 = fmaxf(m0, v0); m1 = fmaxf(m1, v1v);
    }
#pragma unroll
    for (int off = 32; off; off >>= 1) {
      m0 = fmaxf(m0, __shfl_xor(m0, off));
      m1 = fmaxf(m1, __shfl_xor(m1, off));
    }
    float l0 = 0.f, l1 = 0.f;
    for (int j = lane; j < dn; j += 64) {
      int s = srcI[eid[st + j]];
      float v0 = A1[(size_t)s * 8 + 2 * PASS] + ad0;
      float v1v = A1[(size_t)s * 8 + 2 * PASS + 1] + ad1;
      v0 = v0 > 0.f ? v0 : 0.2f * v0;
      v1v = v1v > 0.f ? v1v : 0.2f * v1v;
      l0 += __expf(v0 - m0); l1 += __expf(v1v - m1);
    }
#pragma unroll
    for (int off = 32; off; off >>= 1) {
      l0 += __shfl_xor(l0, off);
      l1 += __shfl_xor(l1, off);
    }
    const float mh = hL ? m1 : m0;
    const float lh = hL ? l1 : l0;
    const float adh = hL ? ad1 : ad0;
    const float inv = 1.0f / lh;
    for (int j = 0; j < dn; ++j) {
      int s = srcI[eid[st + j]];
      float v = A1[(size_t)s * 8 + 2 * PASS + hL] + adh;
      v = v > 0.f ? v : 0.2f * v;
      float alpha = __expf(v - mh) * inv;
      unsigned int u = *(const unsigned int*)(xs1h + (size_t)s * 128 + c);
      a0 += alpha * __uint_as_float(u << 16);
      a1 += alpha * __uint_as_float(u & 0xFFFF0000u);
    }
  }

  const int gc = 128 * PASS + c;
  float h0 = a0 + b1f[gc], h1v = a1 + b1f[gc + 1];
  h0 = h0 > 0.f ? h0 : 0.f;
  h1v = h1v > 0.f ? h1v : 0.f;
  lds_h[wid][c] = h0;
  lds_h[wid][c + 1] = h1v;
  // layer-2 logit partials via fused vectors (algebraically == h@W2@att2)
  float ps = h0 * v2s[gc] + h1v * v2s[gc + 1];
  float pd = h0 * v2d[gc] + h1v * v2d[gc + 1];
#pragma unroll
  for (int off = 1; off <= 32; off <<= 1) {
    ps += __shfl_xor(ps, off);
    pd += __shfl_xor(pd, off);
  }
  __syncthreads();
  // xs2 partial: column lane of h @ W2s, via transposed W2sT (dwordx4 loads)
  float sum = 0.f;
  const uint4* Wp4 = (const uint4*)((const unsigned int*)W2sT + lane * 128 + PASS * 64);
#pragma unroll 4
  for (int ch = 0; ch < 16; ++ch) {
    uint4 wv = Wp4[ch];
    const unsigned int wu[4] = {wv.x, wv.y, wv.z, wv.w};
#pragma unroll
    for (int d = 0; d < 4; ++d) {
      float hk0 = lds_h[wid][ch * 8 + 2 * d];
      float hk1 = lds_h[wid][ch * 8 + 2 * d + 1];
      sum += hk0 * __uint_as_float(wu[d] << 16);
      sum += hk1 * __uint_as_float(wu[d] & 0xFFFF0000u);
    }
  }
  if (valid) {
    size_t o = (size_t)n * 64 + lane;
    if (PASS == 0) {
      xs2[o] = f2bf(sum);
      if (lane == 0) { A2[(size_t)n * 2] = ps; A2[(size_t)n * 2 + 1] = pd; }
    } else {
      xs2[o] = f2bf(bf2f(xs2[o]) + sum);
      if (lane == 0) { A2[(size_t)n * 2] += ps; A2[(size_t)n * 2 + 1] += pd; }
    }
  }
}

// layer-2 aggregation, one wave per node. FLOAT32 output.
__global__ __launch_bounds__(256) void node2(const int* __restrict__ rowst,
    const int* __restrict__ deg, const int* __restrict__ eid,
    const int* __restrict__ srcI, const float* __restrict__ A2,
    const unsigned short* __restrict__ xs2, const float* __restrict__ b2f,
    float* __restrict__ out, int N) {
  __shared__ int   s_sh[4][64];
  __shared__ float al_sh[4][64];
  const int lane = threadIdx.x & 63;
  const int wid = threadIdx.x >> 6;
  const int n = blockIdx.x * 4 + wid;
  if (n >= N) return;  // wave-uniform, no block barriers used
  const int st = rowst[n], dn = deg[n];
  const float ad = A2[(size_t)n * 2 + 1];
  float acc = 0.f;
  if (dn <= 64) {
    int s = 0; float v = NEG_INF;
    if (lane < dn) {
      s = srcI[eid[st + lane]];
      v = A2[(size_t)s * 2] + ad;
      v = v > 0.f ? v : 0.2f * v;
    }
    float m = v;
#pragma unroll
    for (int off = 32; off; off >>= 1) m = fmaxf(m, __shfl_xor(m, off));
    float e = (lane < dn) ? __expf(v - m) : 0.f;
    float l = e;
#pragma unroll
    for (int off = 32; off; off >>= 1) l += __shfl_xor(l, off);
    if (lane < dn) { s_sh[wid][lane] = s; al_sh[wid][lane] = e / l; }
    for (int j = 0; j < dn; ++j) {
      int sj = s_sh[wid][j];
      acc += al_sh[wid][j] * bf2f(xs2[(size_t)sj * 64 + lane]);
    }
  } else {
    float m = NEG_INF;
    for (int j = lane; j < dn; j += 64) {
      int s = srcI[eid[st + j]];
      float v = A2[(size_t)s * 2] + ad;
      v = v > 0.f ? v : 0.2f * v;
      m = fmaxf(m, v);
    }
#pragma unroll
    for (int off = 32; off; off >>= 1) m = fmaxf(m, __shfl_xor(m, off));
    float l = 0.f;
    for (int j = lane; j < dn; j += 64) {
      int s = srcI[eid[st + j]];
      float v = A2[(size_t)s * 2] + ad;
      v = v > 0.f ? v : 0.2f * v;
      l += __expf(v - m);
    }
#pragma unroll
    for (int off = 32; off; off >>= 1) l += __shfl_xor(l, off);
    float inv = 1.0f / l;
    for (int j = 0; j < dn; ++j) {
      int s = srcI[eid[st + j]];
      float v = A2[(size_t)s * 2] + ad;
      v = v > 0.f ? v : 0.2f * v;
      acc += __expf(v - m) * inv * bf2f(xs2[(size_t)s * 64 + lane]);
    }
  }
  out[(size_t)n * 64 + lane] = acc + b2f[lane];
}

extern "C" void kernel_launch(void* const* d_in, const int* in_sizes, int n_in,
                              void* d_out, int out_size, void* d_ws, size_t ws_size,
                              hipStream_t stream) {
  const int F = 128, H1 = 4, C1 = 64, HC1 = 256, C2 = 64;
  const int N  = in_sizes[0] / F;
  const int E  = in_sizes[1] / 2;
  const int EP = E + N;
  (void)n_in;

  char* w = (char*)d_ws;
  size_t off = 0;
  auto alloc = [&](size_t bytes) -> char* {
    char* p = w + off;
    off = (off + bytes + 255) & ~(size_t)255;
    return p;
  };
  int* flags  = (int*)alloc(256);
  int* srcI   = (int*)alloc((size_t)EP * 4);
  int* dstI   = (int*)alloc((size_t)EP * 4);       // overlaid by A1 later
  int* degcur = (int*)alloc((size_t)2 * N * 4);    // zeroed  (start of zero blk)
  int* deg    = degcur;
  int* cursor = degcur + N;
  unsigned short* W1ext = (unsigned short*)alloc(128 * 16 * 2);  // zeroed too
  size_t zero_bytes = (size_t)((char*)W1ext + 128 * 16 * 2 - (char*)degcur);
  int* rowst  = (int*)alloc((size_t)N * 4);
  int* bsum   = (int*)alloc(1024);
  unsigned short* W1c  = (unsigned short*)alloc((size_t)F * HC1 * 2);
  unsigned short* W2sT = (unsigned short*)alloc((size_t)HC1 * C2 * 2);
  float* v1   = (float*)alloc((size_t)F * 8 * 4);
  float* v2s  = (float*)alloc(256 * 4);
  float* v2d  = (float*)alloc(256 * 4);
  float* b1f  = (float*)alloc(256 * 4);
  float* b2f  = (float*)alloc(64 * 4);
  int*   eid  = (int*)alloc((size_t)EP * 4);
  unsigned short* xs1h = (unsigned short*)alloc((size_t)N * 128 * 2);
  unsigned short* xs2  = (unsigned short*)alloc((size_t)N * C2 * 2);
  float* A2 = (float*)alloc((size_t)N * 2 * 4);
  float* A1 = (float*)dstI;  // overlay after CSR build (1.6MB <= 1.8MB)
  const size_t need = off;   // ~25.6 MB

  if (ws_size < need) {  // canary: report ws MB via output
    fill_out_kernel<<<cdiv(out_size, 256), 256, 0, stream>>>(
        (float*)d_out, out_size, 131072.0f + 1024.0f * (float)(ws_size >> 20));
    return;
  }

  hipMemsetAsync(degcur, 0, zero_bytes, stream);
  detect_kernel<<<1, 256, 0, stream>>>((const unsigned short*)d_in[0],
                                       (const unsigned int*)d_in[1], flags);
  canon_edges<<<cdiv(EP, 256), 256, 0, stream>>>(d_in[1], E, EP, N, flags, srcI, dstI);
  canon_bf16<<<cdiv(F * HC1, 256), 256, 0, stream>>>(d_in[2], W1c, F * HC1, flags);
  transpose_w2<<<cdiv(256 * 64, 256), 256, 0, stream>>>(d_in[7], flags, W2sT);
  to_f32<<<1, 256, 0, stream>>>(d_in[6], b1f, 256, flags);
  to_f32<<<1, 256, 0, stream>>>(d_in[11], b2f, 64, flags);
  make_v<<<cdiv(F * H1, 256), 256, 0, stream>>>(d_in[2], d_in[4], flags, v1, F, H1, C1, 8, 0);
  make_v<<<cdiv(F * H1, 256), 256, 0, stream>>>(d_in[3], d_in[5], flags, v1, F, H1, C1, 8, 4);
  make_v<<<1, 256, 0, stream>>>(d_in[7], d_in[9], flags, v2s, HC1, 1, C2, 1, 0);
  make_v<<<1, 256, 0, stream>>>(d_in[8], d_in[10], flags, v2d, HC1, 1, C2, 1, 0);
  v1_to_bf16<<<4, 256, 0, stream>>>(v1, W1ext);

  count_deg<<<cdiv(EP, 256), 256, 0, stream>>>(dstI, EP, deg);
  const int nb = cdiv(N, 256);
  scan1<<<nb, 256, 0, stream>>>(deg, N, rowst, bsum);
  scan2<<<1, 256, 0, stream>>>(bsum, nb);
  scan3<<<nb, 256, 0, stream>>>(rowst, deg, bsum, N);
  fill_eid<<<cdiv(EP, 256), 256, 0, stream>>>(dstI, EP, rowst, cursor, eid);

  // pass 0: xs1 cols 0..127 + A1 (9th col-tile); A1 overlays dead dstI
  gemm_mfma<9, 1><<<cdiv(N, 64), 256, 0, stream>>>(d_in[0], flags, W1c, 0,
                                                   W1ext, xs1h, A1, N);
  node1_fused<0><<<cdiv(N, 4), 256, 0, stream>>>(rowst, deg, eid, srcI, A1, xs1h,
                                                 b1f, W2sT, v2s, v2d, xs2, A2, N);
  gemm_mfma<8, 0><<<cdiv(N, 64), 256, 0, stream>>>(d_in[0], flags, W1c, 128,
                                                   W1ext, xs1h, A1, N);
  node1_fused<1><<<cdiv(N, 4), 256, 0, stream>>>(rowst, deg, eid, srcI, A1, xs1h,
                                                 b1f, W2sT, v2s, v2d, xs2, A2, N);

  node2<<<cdiv(N, 4), 256, 0, stream>>>(rowst, deg, eid, srcI, A2, xs2, b2f,
                                        (float*)d_out, N);
}

// Round 8
// 473.223 us; speedup vs baseline: 2.9749x; 1.0842x over previous
//
#include <hip/hip_runtime.h>

// ---------------------------------------------------------------------------
// GAT 2-layer forward (N=50k, F=128, L1: H=4 x 64, L2: 1 x 64), MI355X.
// Round 8: node1 merged to ONE pass over all 4 heads (full 25.6MB xs1; ws>=59MB
// per R2 evidence); gemm merged to one dispatch (2-phase LDS staging); setup
// consolidated 8->1 prep kernel + fused canon_edges/count_deg. 11 dispatches.
// ---------------------------------------------------------------------------

static inline int cdiv(int a, int b) { return (a + b - 1) / b; }

typedef __attribute__((ext_vector_type(8))) short short8;
typedef __attribute__((ext_vector_type(4))) float floatx4;

__device__ __forceinline__ float bf2f(unsigned short u) {
  return __uint_as_float(((unsigned int)u) << 16);
}
__device__ __forceinline__ unsigned short f2bf(float f) {  // RNE
  unsigned int u = __float_as_uint(f);
  unsigned int r = (u + 0x7FFFu + ((u >> 16) & 1u)) >> 16;
  return (unsigned short)r;
}
__device__ __forceinline__ float ldv(const void* p, int i, int bf) {
  return bf ? bf2f(((const unsigned short*)p)[i]) : ((const float*)p)[i];
}
#define NEG_INF (-__builtin_inff())

// flags[0]=1 if float tensors are bf16 (else f32); flags[1]=1 if edges int64
__global__ void detect_kernel(const unsigned short* __restrict__ xu,
                              const unsigned int* __restrict__ eu,
                              int* __restrict__ flags) {
  __shared__ int c0, c1;
  if (threadIdx.x == 0) { c0 = 0; c1 = 0; }
  __syncthreads();
  int l0 = 0, l1 = 0;
  for (int i = threadIdx.x; i < 1024; i += 256) {
    int e0 = (xu[2 * i] >> 7) & 0xFF;
    if (e0 >= 100 && e0 <= 141) l0++;
    if (eu[2 * i + 1] == 0u) l1++;
  }
  atomicAdd(&c0, l0); atomicAdd(&c1, l1);
  __syncthreads();
  if (threadIdx.x == 0) {
    flags[0] = (c0 > 512) ? 1 : 0;
    flags[1] = (c1 > 512) ? 1 : 0;
  }
}

__global__ void fill_out_kernel(float* __restrict__ out, int n, float val) {
  int t = blockIdx.x * blockDim.x + threadIdx.x;
  if (t < n) out[t] = val;
}

// One consolidated prep kernel. Block roles:
//  b in [0,128)   : canonicalize W1s -> W1c bf16 (32768 el)
//  b in [128,192) : W2sT[col*256+k] = bf16(W2s[k*64+col]) (16384 el)
//  b == 192       : W1ext[k*16+q] = bf16(sum_c W1{s,d}[k,qh*64+c]*att1{s,d}[qh,c]),
//                   cols 8..15 zeroed
//  b == 193       : v2s/v2d fused vectors (256 each)
//  b == 194       : b1f (256) + b2f (64)
__global__ void prep_kernel(const void* __restrict__ W1s, const void* __restrict__ W1d,
                            const void* __restrict__ att1s, const void* __restrict__ att1d,
                            const void* __restrict__ W2s, const void* __restrict__ W2d,
                            const void* __restrict__ att2s, const void* __restrict__ att2d,
                            const void* __restrict__ b1, const void* __restrict__ b2,
                            const int* __restrict__ flags,
                            unsigned short* __restrict__ W1c,
                            unsigned short* __restrict__ W2sT,
                            unsigned short* __restrict__ W1ext,
                            float* __restrict__ v2s, float* __restrict__ v2d,
                            float* __restrict__ b1f, float* __restrict__ b2f) {
  const int b = blockIdx.x, t = threadIdx.x, bf = flags[0];
  if (b < 128) {
    int i = b * 256 + t;
    W1c[i] = f2bf(ldv(W1s, i, bf));
  } else if (b < 192) {
    int i = (b - 128) * 256 + t;
    int k = i >> 6, col = i & 63;
    W2sT[col * 256 + k] = f2bf(ldv(W2s, i, bf));
  } else if (b == 192) {
    for (int r = 0; r < 4; ++r) {
      int idx = r * 256 + t;           // 0..1023
      int k = idx >> 3, q = idx & 7;
      int h = q & 3;
      const void* W = (q < 4) ? W1s : W1d;
      const void* A = (q < 4) ? att1s : att1d;
      float s = 0.f;
      for (int c = 0; c < 64; ++c)
        s += ldv(W, k * 256 + h * 64 + c, bf) * ldv(A, h * 64 + c, bf);
      W1ext[k * 16 + q] = f2bf(s);
      W1ext[k * 16 + 8 + q] = 0;       // zero cols 8..15
    }
  } else if (b == 193) {
    for (int r = 0; r < 2; ++r) {
      int idx = r * 256 + t;           // 0..511
      int k = idx & 255;
      const void* W = (idx < 256) ? W2s : W2d;
      const void* A = (idx < 256) ? att2s : att2d;
      float s = 0.f;
      for (int c = 0; c < 64; ++c) s += ldv(W, k * 64 + c, bf) * ldv(A, c, bf);
      if (idx < 256) v2s[k] = s; else v2d[k] = s;
    }
  } else {
    if (t < 256) b1f[t] = ldv(b1, t, bf);
    if (t < 64)  b2f[t] = ldv(b2, t, bf);
  }
}

// edges -> srcI/dstI + degree count (fused)
__global__ void canon_edges_deg(const void* __restrict__ ei, int E, int EP, int Nn,
                                const int* __restrict__ flags,
                                int* __restrict__ srcI, int* __restrict__ dstI,
                                int* __restrict__ deg) {
  int t = blockIdx.x * blockDim.x + threadIdx.x;
  if (t >= EP) return;
  int s, d;
  if (t < E) {
    if (flags[1]) {
      const unsigned int* p = (const unsigned int*)ei;
      s = (int)p[2 * (size_t)t];
      d = (int)p[2 * ((size_t)E + t)];
    } else {
      const int* p = (const int*)ei;
      s = p[t]; d = p[E + t];
    }
  } else { s = t - E; d = s; }
  if ((unsigned)s >= (unsigned)Nn) s = 0;
  if ((unsigned)d >= (unsigned)Nn) d = 0;
  srcI[t] = s; dstI[t] = d;
  atomicAdd(&deg[d], 1);
}

// ---- CSR scan ----
__global__ void scan1(const int* __restrict__ deg, int N,
                      int* __restrict__ incl, int* __restrict__ bsum) {
  __shared__ int s[256];
  int i = blockIdx.x * 256 + threadIdx.x;
  int v = (i < N) ? deg[i] : 0;
  s[threadIdx.x] = v;
  __syncthreads();
  for (int off = 1; off < 256; off <<= 1) {
    int add = (threadIdx.x >= off) ? s[threadIdx.x - off] : 0;
    __syncthreads();
    s[threadIdx.x] += add;
    __syncthreads();
  }
  if (i < N) incl[i] = s[threadIdx.x];
  if (threadIdx.x == 255) bsum[blockIdx.x] = s[255];
}

__global__ void scan2(int* __restrict__ bsum, int nb) {
  __shared__ int s[256];
  int t = threadIdx.x;
  int v = (t < nb) ? bsum[t] : 0;
  s[t] = v;
  __syncthreads();
  for (int off = 1; off < 256; off <<= 1) {
    int add = (t >= off) ? s[t - off] : 0;
    __syncthreads();
    s[t] += add;
    __syncthreads();
  }
  if (t < nb) bsum[t] = s[t] - v;
}

__global__ void scan3(int* __restrict__ incl, const int* __restrict__ deg,
                      const int* __restrict__ bsum, int N) {
  int i = blockIdx.x * blockDim.x + threadIdx.x;
  if (i >= N) return;
  incl[i] = incl[i] + bsum[i >> 8] - deg[i];
}

__global__ void fill_eid(const int* __restrict__ dstI, int EP,
                         const int* __restrict__ rowst, int* __restrict__ cursor,
                         int* __restrict__ eid) {
  int t = blockIdx.x * blockDim.x + threadIdx.x;
  if (t >= EP) return;
  int d = dstI[t];
  int pos = atomicAdd(&cursor[d], 1);
  eid[rowst[d] + pos] = t;
}

// ---- MFMA GEMM, single dispatch: xs1 = x @ W1 (all 256 cols) + A1 = x @ v1.
// Block = 4 waves, 64 rows. Two LDS staging phases (9 tiles then 8 tiles).
__global__ __launch_bounds__(256) void gemm_full(
    const void* __restrict__ X, const int* __restrict__ flags,
    const unsigned short* __restrict__ W1c, const unsigned short* __restrict__ W1ext,
    unsigned short* __restrict__ xs1, float* __restrict__ A1, int M) {
  __shared__ unsigned short Wlds[9 * 16 * 136];
  const int t = threadIdx.x;
  const int lane = t & 63, wid = t >> 6;
  const int quad = lane >> 4, m16 = lane & 15;
  const int r0 = blockIdx.x * 64 + wid * 16;
  const int arow = min(r0 + m16, M - 1);
  // A fragments: A[m=lane&15][k=quad*8+j]
  short8 af[4];
  if (flags[0]) {
    const uint4* Xr = (const uint4*)((const unsigned int*)X + (size_t)arow * 64);
#pragma unroll
    for (int ks = 0; ks < 4; ++ks)
      af[ks] = __builtin_bit_cast(short8, Xr[ks * 4 + quad]);
  } else {
    const float* Xr = (const float*)X + (size_t)arow * 128;
#pragma unroll
    for (int ks = 0; ks < 4; ++ks) {
      short8 v;
#pragma unroll
      for (int j = 0; j < 8; ++j) v[j] = (short)f2bf(Xr[ks * 32 + quad * 8 + j]);
      af[ks] = v;
    }
  }
  // ---- phase 0: stage cols 0..127 (+A1 tile at 128..143), compute 9 tiles
  if (t < 144) {
    for (int k0 = 0; k0 < 128; k0 += 4) {
      unsigned int u0, u1;
      if (t < 128) {
        const unsigned short* p = W1c + (size_t)k0 * 256 + t;
        u0 = (unsigned int)p[0] | ((unsigned int)p[256] << 16);
        u1 = (unsigned int)p[512] | ((unsigned int)p[768] << 16);
      } else {
        const unsigned short* p = W1ext + (size_t)k0 * 16 + (t - 128);
        u0 = (unsigned int)p[0] | ((unsigned int)p[16] << 16);
        u1 = (unsigned int)p[32] | ((unsigned int)p[48] << 16);
      }
      *(uint2*)&Wlds[t * 136 + k0] = make_uint2(u0, u1);
    }
  }
  __syncthreads();
  for (int ct = 0; ct < 9; ++ct) {
    floatx4 acc = {0.f, 0.f, 0.f, 0.f};
    const unsigned short* wl = &Wlds[(ct * 16 + m16) * 136];
#pragma unroll
    for (int ks = 0; ks < 4; ++ks) {
      short8 bfv = *(const short8*)(wl + ks * 32 + quad * 8);
      acc = __builtin_amdgcn_mfma_f32_16x16x32_bf16(af[ks], bfv, acc, 0, 0, 0);
    }
    if (ct == 8) {          // A1 tile: col = m16 (<8), row = quad*4+reg
      if (m16 < 8) {
#pragma unroll
        for (int r = 0; r < 4; ++r) {
          int row = r0 + quad * 4 + r;
          if (row < M) A1[(size_t)row * 8 + m16] = acc[r];
        }
      }
    } else {
#pragma unroll
      for (int r = 0; r < 4; ++r) {
        int row = r0 + quad * 4 + r;
        if (row < M) xs1[(size_t)row * 256 + ct * 16 + m16] = f2bf(acc[r]);
      }
    }
  }
  // ---- phase 1: stage cols 128..255, compute 8 tiles
  __syncthreads();
  if (t < 128) {
    for (int k0 = 0; k0 < 128; k0 += 4) {
      const unsigned short* p = W1c + (size_t)k0 * 256 + 128 + t;
      unsigned int u0 = (unsigned int)p[0] | ((unsigned int)p[256] << 16);
      unsigned int u1 = (unsigned int)p[512] | ((unsigned int)p[768] << 16);
      *(uint2*)&Wlds[t * 136 + k0] = make_uint2(u0, u1);
    }
  }
  __syncthreads();
  for (int ct = 0; ct < 8; ++ct) {
    floatx4 acc = {0.f, 0.f, 0.f, 0.f};
    const unsigned short* wl = &Wlds[(ct * 16 + m16) * 136];
#pragma unroll
    for (int ks = 0; ks < 4; ++ks) {
      short8 bfv = *(const short8*)(wl + ks * 32 + quad * 8);
      acc = __builtin_amdgcn_mfma_f32_16x16x32_bf16(af[ks], bfv, acc, 0, 0, 0);
    }
#pragma unroll
    for (int r = 0; r < 4; ++r) {
      int row = r0 + quad * 4 + r;
      if (row < M) xs1[(size_t)row * 256 + 128 + ct * 16 + m16] = f2bf(acc[r]);
    }
  }
}

// ---- node1 merged: all 4 heads in one pass. One wave per node. Fused layer-2
// partials: xs2 = h@W2s (via W2sT), A2 logits via v2s/v2d fused vectors.
__global__ __launch_bounds__(256) void node1_merged(
    const int* __restrict__ rowst, const int* __restrict__ deg,
    const int* __restrict__ eid, const int* __restrict__ srcI,
    const float* __restrict__ A1, const unsigned short* __restrict__ xs1,
    const float* __restrict__ b1f, const unsigned short* __restrict__ W2sT,
    const float* __restrict__ v2s, const float* __restrict__ v2d,
    unsigned short* __restrict__ xs2, float* __restrict__ A2, int N) {
  __shared__ float lds_h[4][256];
  __shared__ int   s_sh[4][64];
  __shared__ float al_sh[4][64][4];
  const int lane = threadIdx.x & 63;
  const int wid = threadIdx.x >> 6;
  const int nraw = blockIdx.x * 4 + wid;
  const bool valid = nraw < N;
  const int n = valid ? nraw : (N - 1);
  const int st = rowst[n], dn = deg[n];
  const float4 ad4 = *(const float4*)(A1 + (size_t)n * 8 + 4);
  const float ad[4] = {ad4.x, ad4.y, ad4.z, ad4.w};
  const int gc = 4 * lane;          // this lane's 4 channels
  const int hL = lane >> 4;         // their head
  float acc[4] = {0.f, 0.f, 0.f, 0.f};

  if (dn <= 64) {
    // one edge per lane; alphas for all 4 heads cached in per-wave LDS
    int s = 0;
    float v[4] = {NEG_INF, NEG_INF, NEG_INF, NEG_INF};
    if (lane < dn) {
      s = srcI[eid[st + lane]];
      const float4 as4 = *(const float4*)(A1 + (size_t)s * 8);
      const float as[4] = {as4.x, as4.y, as4.z, as4.w};
#pragma unroll
      for (int h = 0; h < 4; ++h) {
        float x = as[h] + ad[h];
        v[h] = x > 0.f ? x : 0.2f * x;
      }
    }
    float m[4], l[4];
#pragma unroll
    for (int h = 0; h < 4; ++h) {
      m[h] = v[h];
#pragma unroll
      for (int off = 32; off; off >>= 1) m[h] = fmaxf(m[h], __shfl_xor(m[h], off));
      float e = (lane < dn) ? __expf(v[h] - m[h]) : 0.f;
      l[h] = e;
#pragma unroll
      for (int off = 32; off; off >>= 1) l[h] += __shfl_xor(l[h], off);
      v[h] = e;  // reuse as exp value
    }
    if (lane < dn) {
      s_sh[wid][lane] = s;
      float4 al = {v[0] / l[0], v[1] / l[1], v[2] / l[2], v[3] / l[3]};
      *(float4*)&al_sh[wid][lane][0] = al;
    }
    int j = 0;
    for (; j + 2 <= dn; j += 2) {
      int s0 = s_sh[wid][j], s1 = s_sh[wid][j + 1];
      float a0 = al_sh[wid][j][hL], a1 = al_sh[wid][j + 1][hL];
      uint2 u0 = *(const uint2*)(xs1 + (size_t)s0 * 256 + gc);
      uint2 u1 = *(const uint2*)(xs1 + (size_t)s1 * 256 + gc);
      acc[0] += a0 * __uint_as_float(u0.x << 16);
      acc[1] += a0 * __uint_as_float(u0.x & 0xFFFF0000u);
      acc[2] += a0 * __uint_as_float(u0.y << 16);
      acc[3] += a0 * __uint_as_float(u0.y & 0xFFFF0000u);
      acc[0] += a1 * __uint_as_float(u1.x << 16);
      acc[1] += a1 * __uint_as_float(u1.x & 0xFFFF0000u);
      acc[2] += a1 * __uint_as_float(u1.y << 16);
      acc[3] += a1 * __uint_as_float(u1.y & 0xFFFF0000u);
    }
    if (j < dn) {
      int s0 = s_sh[wid][j];
      float a0 = al_sh[wid][j][hL];
      uint2 u0 = *(const uint2*)(xs1 + (size_t)s0 * 256 + gc);
      acc[0] += a0 * __uint_as_float(u0.x << 16);
      acc[1] += a0 * __uint_as_float(u0.x & 0xFFFF0000u);
      acc[2] += a0 * __uint_as_float(u0.y << 16);
      acc[3] += a0 * __uint_as_float(u0.y & 0xFFFF0000u);
    }
  } else {
    // fallback: strided two-pass softmax over 4 heads, serial gather
    float m[4] = {NEG_INF, NEG_INF, NEG_INF, NEG_INF};
    for (int j = lane; j < dn; j += 64) {
      int s = srcI[eid[st + j]];
      const float4 as4 = *(const float4*)(A1 + (size_t)s * 8);
      const float as[4] = {as4.x, as4.y, as4.z, as4.w};
#pragma unroll
      for (int h = 0; h < 4; ++h) {
        float x = as[h] + ad[h];
        x = x > 0.f ? x : 0.2f * x;
        m[h] = fmaxf(m[h], x);
      }
    }
#pragma unroll
    for (int h = 0; h < 4; ++h)
#pragma unroll
      for (int off = 32; off; off >>= 1) m[h] = fmaxf(m[h], __shfl_xor(m[h], off));
    float l[4] = {0.f, 0.f, 0.f, 0.f};
    for (int j = lane; j < dn; j += 64) {
      int s = srcI[eid[st + j]];
      const float4 as4 = *(const float4*)(A1 + (size_t)s * 8);
      const float as[4] = {as4.x, as4.y, as4.z, as4.w};
#pragma unroll
      for (int h = 0; h < 4; ++h) {
        float x = as[h] + ad[h];
        x = x > 0.f ? x : 0.2f * x;
        l[h] += __expf(x - m[h]);
      }
    }
#pragma unroll
    for (int h = 0; h < 4; ++h)
#pragma unroll
      for (int off = 32; off; off >>= 1) l[h] += __shfl_xor(l[h], off);
    const float mh = m[hL], inv = 1.0f / l[hL], adh = ad[hL];
    for (int j = 0; j < dn; ++j) {
      int s = srcI[eid[st + j]];
      float x = A1[(size_t)s * 8 + hL] + adh;
      x = x > 0.f ? x : 0.2f * x;
      float alpha = __expf(x - mh) * inv;
      uint2 u = *(const uint2*)(xs1 + (size_t)s * 256 + gc);
      acc[0] += alpha * __uint_as_float(u.x << 16);
      acc[1] += alpha * __uint_as_float(u.x & 0xFFFF0000u);
      acc[2] += alpha * __uint_as_float(u.y << 16);
      acc[3] += alpha * __uint_as_float(u.y & 0xFFFF0000u);
    }
  }

  // epilogue: bias+relu, layer-2 logit partials, xs2 column dot
  const float4 bb = *(const float4*)(b1f + gc);
  float h0 = acc[0] + bb.x, h1 = acc[1] + bb.y;
  float h2 = acc[2] + bb.z, h3 = acc[3] + bb.w;
  h0 = h0 > 0.f ? h0 : 0.f; h1 = h1 > 0.f ? h1 : 0.f;
  h2 = h2 > 0.f ? h2 : 0.f; h3 = h3 > 0.f ? h3 : 0.f;
  float4 hv = {h0, h1, h2, h3};
  *(float4*)&lds_h[wid][gc] = hv;
  const float4 vs = *(const float4*)(v2s + gc);
  const float4 vd = *(const float4*)(v2d + gc);
  float ps = h0 * vs.x + h1 * vs.y + h2 * vs.z + h3 * vs.w;
  float pd = h0 * vd.x + h1 * vd.y + h2 * vd.z + h3 * vd.w;
#pragma unroll
  for (int off = 1; off <= 32; off <<= 1) {
    ps += __shfl_xor(ps, off);
    pd += __shfl_xor(pd, off);
  }
  __syncthreads();
  float sum = 0.f;
  const uint4* Wp4 = (const uint4*)((const unsigned int*)W2sT + lane * 128);
#pragma unroll 8
  for (int ch = 0; ch < 32; ++ch) {
    uint4 wv = Wp4[ch];
    const unsigned int wu[4] = {wv.x, wv.y, wv.z, wv.w};
#pragma unroll
    for (int d = 0; d < 4; ++d) {
      sum += lds_h[wid][ch * 8 + 2 * d]     * __uint_as_float(wu[d] << 16);
      sum += lds_h[wid][ch * 8 + 2 * d + 1] * __uint_as_float(wu[d] & 0xFFFF0000u);
    }
  }
  if (valid) {
    xs2[(size_t)n * 64 + lane] = f2bf(sum);
    if (lane == 0) { A2[(size_t)n * 2] = ps; A2[(size_t)n * 2 + 1] = pd; }
  }
}

// layer-2 aggregation, one wave per node. FLOAT32 output.
__global__ __launch_bounds__(256) void node2(const int* __restrict__ rowst,
    const int* __restrict__ deg, const int* __restrict__ eid,
    const int* __restrict__ srcI, const float* __restrict__ A2,
    const unsigned short* __restrict__ xs2, const float* __restrict__ b2f,
    float* __restrict__ out, int N) {
  __shared__ int   s_sh[4][64];
  __shared__ float al_sh[4][64];
  const int lane = threadIdx.x & 63;
  const int wid = threadIdx.x >> 6;
  const int n = blockIdx.x * 4 + wid;
  if (n >= N) return;  // wave-uniform
  const int st = rowst[n], dn = deg[n];
  const float ad = A2[(size_t)n * 2 + 1];
  float acc = 0.f;
  if (dn <= 64) {
    int s = 0; float v = NEG_INF;
    if (lane < dn) {
      s = srcI[eid[st + lane]];
      v = A2[(size_t)s * 2] + ad;
      v = v > 0.f ? v : 0.2f * v;
    }
    float m = v;
#pragma unroll
    for (int off = 32; off; off >>= 1) m = fmaxf(m, __shfl_xor(m, off));
    float e = (lane < dn) ? __expf(v - m) : 0.f;
    float l = e;
#pragma unroll
    for (int off = 32; off; off >>= 1) l += __shfl_xor(l, off);
    if (lane < dn) { s_sh[wid][lane] = s; al_sh[wid][lane] = e / l; }
    int j = 0;
    for (; j + 2 <= dn; j += 2) {
      int s0 = s_sh[wid][j], s1 = s_sh[wid][j + 1];
      float a0 = al_sh[wid][j], a1 = al_sh[wid][j + 1];
      float x0 = bf2f(xs2[(size_t)s0 * 64 + lane]);
      float x1 = bf2f(xs2[(size_t)s1 * 64 + lane]);
      acc += a0 * x0 + a1 * x1;
    }
    if (j < dn)
      acc += al_sh[wid][j] * bf2f(xs2[(size_t)s_sh[wid][j] * 64 + lane]);
  } else {
    float m = NEG_INF;
    for (int j = lane; j < dn; j += 64) {
      int s = srcI[eid[st + j]];
      float v = A2[(size_t)s * 2] + ad;
      v = v > 0.f ? v : 0.2f * v;
      m = fmaxf(m, v);
    }
#pragma unroll
    for (int off = 32; off; off >>= 1) m = fmaxf(m, __shfl_xor(m, off));
    float l = 0.f;
    for (int j = lane; j < dn; j += 64) {
      int s = srcI[eid[st + j]];
      float v = A2[(size_t)s * 2] + ad;
      v = v > 0.f ? v : 0.2f * v;
      l += __expf(v - m);
    }
#pragma unroll
    for (int off = 32; off; off >>= 1) l += __shfl_xor(l, off);
    float inv = 1.0f / l;
    for (int j = 0; j < dn; ++j) {
      int s = srcI[eid[st + j]];
      float v = A2[(size_t)s * 2] + ad;
      v = v > 0.f ? v : 0.2f * v;
      acc += __expf(v - m) * inv * bf2f(xs2[(size_t)s * 64 + lane]);
    }
  }
  out[(size_t)n * 64 + lane] = acc + b2f[lane];
}

extern "C" void kernel_launch(void* const* d_in, const int* in_sizes, int n_in,
                              void* d_out, int out_size, void* d_ws, size_t ws_size,
                              hipStream_t stream) {
  const int F = 128, HC1 = 256, C2 = 64;
  const int N  = in_sizes[0] / F;
  const int E  = in_sizes[1] / 2;
  const int EP = E + N;
  (void)n_in;

  char* w = (char*)d_ws;
  size_t off = 0;
  auto alloc = [&](size_t bytes) -> char* {
    char* p = w + off;
    off = (off + bytes + 255) & ~(size_t)255;
    return p;
  };
  int* flags  = (int*)alloc(256);
  int* srcI   = (int*)alloc((size_t)EP * 4);
  int* dstI   = (int*)alloc((size_t)EP * 4);       // overlaid by A1 later
  int* degcur = (int*)alloc((size_t)2 * N * 4);    // zeroed
  int* deg    = degcur;
  int* cursor = degcur + N;
  int* rowst  = (int*)alloc((size_t)N * 4);
  int* bsum   = (int*)alloc(1024);
  unsigned short* W1c   = (unsigned short*)alloc((size_t)F * HC1 * 2);
  unsigned short* W1ext = (unsigned short*)alloc(128 * 16 * 2);
  unsigned short* W2sT  = (unsigned short*)alloc((size_t)HC1 * C2 * 2);
  float* v2s  = (float*)alloc(256 * 4);
  float* v2d  = (float*)alloc(256 * 4);
  float* b1f  = (float*)alloc(256 * 4);
  float* b2f  = (float*)alloc(64 * 4);
  int*   eid  = (int*)alloc((size_t)EP * 4);
  unsigned short* xs1 = (unsigned short*)alloc((size_t)N * HC1 * 2);  // FULL 25.6MB
  unsigned short* xs2 = (unsigned short*)alloc((size_t)N * C2 * 2);
  float* A2 = (float*)alloc((size_t)N * 2 * 4);
  float* A1 = (float*)dstI;  // overlay after fill_eid (1.6MB <= 1.8MB)
  const size_t need = off;   // ~39 MB (ws >= 59MB per R2 evidence)

  if (ws_size < need) {  // canary: report ws MB via output
    fill_out_kernel<<<cdiv(out_size, 256), 256, 0, stream>>>(
        (float*)d_out, out_size, 131072.0f + 1024.0f * (float)(ws_size >> 20));
    return;
  }

  hipMemsetAsync(degcur, 0, (size_t)2 * N * 4, stream);
  detect_kernel<<<1, 256, 0, stream>>>((const unsigned short*)d_in[0],
                                       (const unsigned int*)d_in[1], flags);
  prep_kernel<<<195, 256, 0, stream>>>(d_in[2], d_in[3], d_in[4], d_in[5],
                                       d_in[7], d_in[8], d_in[9], d_in[10],
                                       d_in[6], d_in[11], flags,
                                       W1c, W2sT, W1ext, v2s, v2d, b1f, b2f);
  canon_edges_deg<<<cdiv(EP, 256), 256, 0, stream>>>(d_in[1], E, EP, N, flags,
                                                     srcI, dstI, deg);
  const int nb = cdiv(N, 256);
  scan1<<<nb, 256, 0, stream>>>(deg, N, rowst, bsum);
  scan2<<<1, 256, 0, stream>>>(bsum, nb);
  scan3<<<nb, 256, 0, stream>>>(rowst, deg, bsum, N);
  fill_eid<<<cdiv(EP, 256), 256, 0, stream>>>(dstI, EP, rowst, cursor, eid);

  gemm_full<<<cdiv(N, 64), 256, 0, stream>>>(d_in[0], flags, W1c, W1ext, xs1, A1, N);
  node1_merged<<<cdiv(N, 4), 256, 0, stream>>>(rowst, deg, eid, srcI, A1, xs1,
                                               b1f, W2sT, v2s, v2d, xs2, A2, N);
  node2<<<cdiv(N, 4), 256, 0, stream>>>(rowst, deg, eid, srcI, A2, xs2, b2f,
                                        (float*)d_out, N);
}

// Round 9
// 347.714 us; speedup vs baseline: 4.0487x; 1.3610x over previous
//
#include <hip/hip_runtime.h>

// ---------------------------------------------------------------------------
// GAT 2-layer forward (N=50k, F=128, L1: H=4 x 64, L2: 1 x 64), MI355X.
// Round 9: node1 epilogue (h@W2s, 256 scalar MACs/lane = dominant VALU cost)
// replaced by block-level MFMA over LDS-packed bf16 h; eid->srcI indirection
// removed (srcS materialized at CSR fill); gather loops unrolled 4x for MLP.
// ---------------------------------------------------------------------------

static inline int cdiv(int a, int b) { return (a + b - 1) / b; }

typedef __attribute__((ext_vector_type(8))) short short8;
typedef __attribute__((ext_vector_type(4))) float floatx4;

__device__ __forceinline__ float bf2f(unsigned short u) {
  return __uint_as_float(((unsigned int)u) << 16);
}
__device__ __forceinline__ unsigned short f2bf(float f) {  // RNE
  unsigned int u = __float_as_uint(f);
  unsigned int r = (u + 0x7FFFu + ((u >> 16) & 1u)) >> 16;
  return (unsigned short)r;
}
__device__ __forceinline__ float ldv(const void* p, int i, int bf) {
  return bf ? bf2f(((const unsigned short*)p)[i]) : ((const float*)p)[i];
}
#define NEG_INF (-__builtin_inff())

__global__ void detect_kernel(const unsigned short* __restrict__ xu,
                              const unsigned int* __restrict__ eu,
                              int* __restrict__ flags) {
  __shared__ int c0, c1;
  if (threadIdx.x == 0) { c0 = 0; c1 = 0; }
  __syncthreads();
  int l0 = 0, l1 = 0;
  for (int i = threadIdx.x; i < 1024; i += 256) {
    int e0 = (xu[2 * i] >> 7) & 0xFF;
    if (e0 >= 100 && e0 <= 141) l0++;
    if (eu[2 * i + 1] == 0u) l1++;
  }
  atomicAdd(&c0, l0); atomicAdd(&c1, l1);
  __syncthreads();
  if (threadIdx.x == 0) {
    flags[0] = (c0 > 512) ? 1 : 0;
    flags[1] = (c1 > 512) ? 1 : 0;
  }
}

__global__ void fill_out_kernel(float* __restrict__ out, int n, float val) {
  int t = blockIdx.x * blockDim.x + threadIdx.x;
  if (t < n) out[t] = val;
}

// One consolidated prep kernel (see R8 comment for block roles).
__global__ void prep_kernel(const void* __restrict__ W1s, const void* __restrict__ W1d,
                            const void* __restrict__ att1s, const void* __restrict__ att1d,
                            const void* __restrict__ W2s, const void* __restrict__ W2d,
                            const void* __restrict__ att2s, const void* __restrict__ att2d,
                            const void* __restrict__ b1, const void* __restrict__ b2,
                            const int* __restrict__ flags,
                            unsigned short* __restrict__ W1c,
                            unsigned short* __restrict__ W2sT,
                            unsigned short* __restrict__ W1ext,
                            float* __restrict__ v2s, float* __restrict__ v2d,
                            float* __restrict__ b1f, float* __restrict__ b2f) {
  const int b = blockIdx.x, t = threadIdx.x, bf = flags[0];
  if (b < 128) {
    int i = b * 256 + t;
    W1c[i] = f2bf(ldv(W1s, i, bf));
  } else if (b < 192) {
    int i = (b - 128) * 256 + t;
    int k = i >> 6, col = i & 63;
    W2sT[col * 256 + k] = f2bf(ldv(W2s, i, bf));
  } else if (b == 192) {
    for (int r = 0; r < 4; ++r) {
      int idx = r * 256 + t;
      int k = idx >> 3, q = idx & 7;
      int h = q & 3;
      const void* W = (q < 4) ? W1s : W1d;
      const void* A = (q < 4) ? att1s : att1d;
      float s = 0.f;
      for (int c = 0; c < 64; ++c)
        s += ldv(W, k * 256 + h * 64 + c, bf) * ldv(A, h * 64 + c, bf);
      W1ext[k * 16 + q] = f2bf(s);
      W1ext[k * 16 + 8 + q] = 0;
    }
  } else if (b == 193) {
    for (int r = 0; r < 2; ++r) {
      int idx = r * 256 + t;
      int k = idx & 255;
      const void* W = (idx < 256) ? W2s : W2d;
      const void* A = (idx < 256) ? att2s : att2d;
      float s = 0.f;
      for (int c = 0; c < 64; ++c) s += ldv(W, k * 64 + c, bf) * ldv(A, c, bf);
      if (idx < 256) v2s[k] = s; else v2d[k] = s;
    }
  } else {
    if (t < 256) b1f[t] = ldv(b1, t, bf);
    if (t < 64)  b2f[t] = ldv(b2, t, bf);
  }
}

__global__ void canon_edges_deg(const void* __restrict__ ei, int E, int EP, int Nn,
                                const int* __restrict__ flags,
                                int* __restrict__ srcI, int* __restrict__ dstI,
                                int* __restrict__ deg) {
  int t = blockIdx.x * blockDim.x + threadIdx.x;
  if (t >= EP) return;
  int s, d;
  if (t < E) {
    if (flags[1]) {
      const unsigned int* p = (const unsigned int*)ei;
      s = (int)p[2 * (size_t)t];
      d = (int)p[2 * ((size_t)E + t)];
    } else {
      const int* p = (const int*)ei;
      s = p[t]; d = p[E + t];
    }
  } else { s = t - E; d = s; }
  if ((unsigned)s >= (unsigned)Nn) s = 0;
  if ((unsigned)d >= (unsigned)Nn) d = 0;
  srcI[t] = s; dstI[t] = d;
  atomicAdd(&deg[d], 1);
}

__global__ void scan1(const int* __restrict__ deg, int N,
                      int* __restrict__ incl, int* __restrict__ bsum) {
  __shared__ int s[256];
  int i = blockIdx.x * 256 + threadIdx.x;
  int v = (i < N) ? deg[i] : 0;
  s[threadIdx.x] = v;
  __syncthreads();
  for (int off = 1; off < 256; off <<= 1) {
    int add = (threadIdx.x >= off) ? s[threadIdx.x - off] : 0;
    __syncthreads();
    s[threadIdx.x] += add;
    __syncthreads();
  }
  if (i < N) incl[i] = s[threadIdx.x];
  if (threadIdx.x == 255) bsum[blockIdx.x] = s[255];
}

__global__ void scan2(int* __restrict__ bsum, int nb) {
  __shared__ int s[256];
  int t = threadIdx.x;
  int v = (t < nb) ? bsum[t] : 0;
  s[t] = v;
  __syncthreads();
  for (int off = 1; off < 256; off <<= 1) {
    int add = (t >= off) ? s[t - off] : 0;
    __syncthreads();
    s[t] += add;
    __syncthreads();
  }
  if (t < nb) bsum[t] = s[t] - v;
}

__global__ void scan3(int* __restrict__ incl, const int* __restrict__ deg,
                      const int* __restrict__ bsum, int N) {
  int i = blockIdx.x * blockDim.x + threadIdx.x;
  if (i >= N) return;
  incl[i] = incl[i] + bsum[i >> 8] - deg[i];
}

// CSR fill: materialize src node id per row slot (kills eid->srcI indirection)
__global__ void fill_srcS(const int* __restrict__ srcI, const int* __restrict__ dstI,
                          int EP, const int* __restrict__ rowst,
                          int* __restrict__ cursor, int* __restrict__ srcS) {
  int t = blockIdx.x * blockDim.x + threadIdx.x;
  if (t >= EP) return;
  int d = dstI[t];
  int pos = atomicAdd(&cursor[d], 1);
  srcS[rowst[d] + pos] = srcI[t];
}

// ---- MFMA GEMM: xs1 = x @ W1 (256 cols) + A1 = x @ v1 (9th tile, pass 0).
__global__ __launch_bounds__(256) void gemm_full(
    const void* __restrict__ X, const int* __restrict__ flags,
    const unsigned short* __restrict__ W1c, const unsigned short* __restrict__ W1ext,
    unsigned short* __restrict__ xs1, float* __restrict__ A1, int M) {
  __shared__ unsigned short Wlds[9 * 16 * 136];
  const int t = threadIdx.x;
  const int lane = t & 63, wid = t >> 6;
  const int quad = lane >> 4, m16 = lane & 15;
  const int r0 = blockIdx.x * 64 + wid * 16;
  const int arow = min(r0 + m16, M - 1);
  short8 af[4];
  if (flags[0]) {
    const uint4* Xr = (const uint4*)((const unsigned int*)X + (size_t)arow * 64);
#pragma unroll
    for (int ks = 0; ks < 4; ++ks)
      af[ks] = __builtin_bit_cast(short8, Xr[ks * 4 + quad]);
  } else {
    const float* Xr = (const float*)X + (size_t)arow * 128;
#pragma unroll
    for (int ks = 0; ks < 4; ++ks) {
      short8 v;
#pragma unroll
      for (int j = 0; j < 8; ++j) v[j] = (short)f2bf(Xr[ks * 32 + quad * 8 + j]);
      af[ks] = v;
    }
  }
  if (t < 144) {
    for (int k0 = 0; k0 < 128; k0 += 4) {
      unsigned int u0, u1;
      if (t < 128) {
        const unsigned short* p = W1c + (size_t)k0 * 256 + t;
        u0 = (unsigned int)p[0] | ((unsigned int)p[256] << 16);
        u1 = (unsigned int)p[512] | ((unsigned int)p[768] << 16);
      } else {
        const unsigned short* p = W1ext + (size_t)k0 * 16 + (t - 128);
        u0 = (unsigned int)p[0] | ((unsigned int)p[16] << 16);
        u1 = (unsigned int)p[32] | ((unsigned int)p[48] << 16);
      }
      *(uint2*)&Wlds[t * 136 + k0] = make_uint2(u0, u1);
    }
  }
  __syncthreads();
  for (int ct = 0; ct < 9; ++ct) {
    floatx4 acc = {0.f, 0.f, 0.f, 0.f};
    const unsigned short* wl = &Wlds[(ct * 16 + m16) * 136];
#pragma unroll
    for (int ks = 0; ks < 4; ++ks) {
      short8 bfv = *(const short8*)(wl + ks * 32 + quad * 8);
      acc = __builtin_amdgcn_mfma_f32_16x16x32_bf16(af[ks], bfv, acc, 0, 0, 0);
    }
    if (ct == 8) {
      if (m16 < 8) {
#pragma unroll
        for (int r = 0; r < 4; ++r) {
          int row = r0 + quad * 4 + r;
          if (row < M) A1[(size_t)row * 8 + m16] = acc[r];
        }
      }
    } else {
#pragma unroll
      for (int r = 0; r < 4; ++r) {
        int row = r0 + quad * 4 + r;
        if (row < M) xs1[(size_t)row * 256 + ct * 16 + m16] = f2bf(acc[r]);
      }
    }
  }
  __syncthreads();
  if (t < 128) {
    for (int k0 = 0; k0 < 128; k0 += 4) {
      const unsigned short* p = W1c + (size_t)k0 * 256 + 128 + t;
      unsigned int u0 = (unsigned int)p[0] | ((unsigned int)p[256] << 16);
      unsigned int u1 = (unsigned int)p[512] | ((unsigned int)p[768] << 16);
      *(uint2*)&Wlds[t * 136 + k0] = make_uint2(u0, u1);
    }
  }
  __syncthreads();
  for (int ct = 0; ct < 8; ++ct) {
    floatx4 acc = {0.f, 0.f, 0.f, 0.f};
    const unsigned short* wl = &Wlds[(ct * 16 + m16) * 136];
#pragma unroll
    for (int ks = 0; ks < 4; ++ks) {
      short8 bfv = *(const short8*)(wl + ks * 32 + quad * 8);
      acc = __builtin_amdgcn_mfma_f32_16x16x32_bf16(af[ks], bfv, acc, 0, 0, 0);
    }
#pragma unroll
    for (int r = 0; r < 4; ++r) {
      int row = r0 + quad * 4 + r;
      if (row < M) xs1[(size_t)row * 256 + 128 + ct * 16 + m16] = f2bf(acc[r]);
    }
  }
}

// ---- node1: softmax + gather (all 4 heads), then BLOCK MFMA epilogue for
// xs2 = h @ W2s (4 nodes x 256 K x 64 cols). One wave per node.
__global__ __launch_bounds__(256) void node1_merged(
    const int* __restrict__ rowst, const int* __restrict__ deg,
    const int* __restrict__ srcS,
    const float* __restrict__ A1, const unsigned short* __restrict__ xs1,
    const float* __restrict__ b1f, const unsigned short* __restrict__ W2sT,
    const float* __restrict__ v2s, const float* __restrict__ v2d,
    unsigned short* __restrict__ xs2, float* __restrict__ A2, int N) {
  __shared__ unsigned short hb[4][256];     // packed bf16 h rows (MFMA A)
  __shared__ int   s_sh[4][64];
  __shared__ float al_sh[4][64][4];
  const int lane = threadIdx.x & 63;
  const int wid = threadIdx.x >> 6;
  const int nraw = blockIdx.x * 4 + wid;
  const bool valid = nraw < N;
  const int n = valid ? nraw : (N - 1);
  const int st = rowst[n], dn = deg[n];
  const float4 ad4 = *(const float4*)(A1 + (size_t)n * 8 + 4);
  const float ad[4] = {ad4.x, ad4.y, ad4.z, ad4.w};
  const int gc = 4 * lane;
  const int hL = lane >> 4;
  float acc[4] = {0.f, 0.f, 0.f, 0.f};

  if (dn <= 64) {
    int s = 0;
    float v[4] = {NEG_INF, NEG_INF, NEG_INF, NEG_INF};
    if (lane < dn) {
      s = srcS[st + lane];                   // coalesced, no indirection
      const float4 as4 = *(const float4*)(A1 + (size_t)s * 8);
      const float as[4] = {as4.x, as4.y, as4.z, as4.w};
#pragma unroll
      for (int h = 0; h < 4; ++h) {
        float x = as[h] + ad[h];
        v[h] = x > 0.f ? x : 0.2f * x;
      }
    }
    float m[4], l[4];
#pragma unroll
    for (int h = 0; h < 4; ++h) {
      m[h] = v[h];
#pragma unroll
      for (int off = 32; off; off >>= 1) m[h] = fmaxf(m[h], __shfl_xor(m[h], off));
      float e = (lane < dn) ? __expf(v[h] - m[h]) : 0.f;
      l[h] = e;
#pragma unroll
      for (int off = 32; off; off >>= 1) l[h] += __shfl_xor(l[h], off);
      v[h] = e;
    }
    if (lane < dn) {
      s_sh[wid][lane] = s;
      float4 al = {v[0] / l[0], v[1] / l[1], v[2] / l[2], v[3] / l[3]};
      *(float4*)&al_sh[wid][lane][0] = al;
    }
    // 4-way unrolled gather for MLP
    int j = 0;
    for (; j + 4 <= dn; j += 4) {
      int s0 = s_sh[wid][j], s1 = s_sh[wid][j + 1];
      int s2 = s_sh[wid][j + 2], s3 = s_sh[wid][j + 3];
      float a0 = al_sh[wid][j][hL],     a1 = al_sh[wid][j + 1][hL];
      float a2 = al_sh[wid][j + 2][hL], a3 = al_sh[wid][j + 3][hL];
      uint2 u0 = *(const uint2*)(xs1 + (size_t)s0 * 256 + gc);
      uint2 u1 = *(const uint2*)(xs1 + (size_t)s1 * 256 + gc);
      uint2 u2 = *(const uint2*)(xs1 + (size_t)s2 * 256 + gc);
      uint2 u3 = *(const uint2*)(xs1 + (size_t)s3 * 256 + gc);
      acc[0] += a0 * __uint_as_float(u0.x << 16);
      acc[1] += a0 * __uint_as_float(u0.x & 0xFFFF0000u);
      acc[2] += a0 * __uint_as_float(u0.y << 16);
      acc[3] += a0 * __uint_as_float(u0.y & 0xFFFF0000u);
      acc[0] += a1 * __uint_as_float(u1.x << 16);
      acc[1] += a1 * __uint_as_float(u1.x & 0xFFFF0000u);
      acc[2] += a1 * __uint_as_float(u1.y << 16);
      acc[3] += a1 * __uint_as_float(u1.y & 0xFFFF0000u);
      acc[0] += a2 * __uint_as_float(u2.x << 16);
      acc[1] += a2 * __uint_as_float(u2.x & 0xFFFF0000u);
      acc[2] += a2 * __uint_as_float(u2.y << 16);
      acc[3] += a2 * __uint_as_float(u2.y & 0xFFFF0000u);
      acc[0] += a3 * __uint_as_float(u3.x << 16);
      acc[1] += a3 * __uint_as_float(u3.x & 0xFFFF0000u);
      acc[2] += a3 * __uint_as_float(u3.y << 16);
      acc[3] += a3 * __uint_as_float(u3.y & 0xFFFF0000u);
    }
    for (; j < dn; ++j) {
      int s0 = s_sh[wid][j];
      float a0 = al_sh[wid][j][hL];
      uint2 u0 = *(const uint2*)(xs1 + (size_t)s0 * 256 + gc);
      acc[0] += a0 * __uint_as_float(u0.x << 16);
      acc[1] += a0 * __uint_as_float(u0.x & 0xFFFF0000u);
      acc[2] += a0 * __uint_as_float(u0.y << 16);
      acc[3] += a0 * __uint_as_float(u0.y & 0xFFFF0000u);
    }
  } else {
    float m[4] = {NEG_INF, NEG_INF, NEG_INF, NEG_INF};
    for (int j = lane; j < dn; j += 64) {
      int s = srcS[st + j];
      const float4 as4 = *(const float4*)(A1 + (size_t)s * 8);
      const float as[4] = {as4.x, as4.y, as4.z, as4.w};
#pragma unroll
      for (int h = 0; h < 4; ++h) {
        float x = as[h] + ad[h];
        x = x > 0.f ? x : 0.2f * x;
        m[h] = fmaxf(m[h], x);
      }
    }
#pragma unroll
    for (int h = 0; h < 4; ++h)
#pragma unroll
      for (int off = 32; off; off >>= 1) m[h] = fmaxf(m[h], __shfl_xor(m[h], off));
    float l[4] = {0.f, 0.f, 0.f, 0.f};
    for (int j = lane; j < dn; j += 64) {
      int s = srcS[st + j];
      const float4 as4 = *(const float4*)(A1 + (size_t)s * 8);
      const float as[4] = {as4.x, as4.y, as4.z, as4.w};
#pragma unroll
      for (int h = 0; h < 4; ++h) {
        float x = as[h] + ad[h];
        x = x > 0.f ? x : 0.2f * x;
        l[h] += __expf(x - m[h]);
      }
    }
#pragma unroll
    for (int h = 0; h < 4; ++h)
#pragma unroll
      for (int off = 32; off; off >>= 1) l[h] += __shfl_xor(l[h], off);
    const float mh = m[hL], inv = 1.0f / l[hL], adh = ad[hL];
    for (int j = 0; j < dn; ++j) {
      int s = srcS[st + j];
      float x = A1[(size_t)s * 8 + hL] + adh;
      x = x > 0.f ? x : 0.2f * x;
      float alpha = __expf(x - mh) * inv;
      uint2 u = *(const uint2*)(xs1 + (size_t)s * 256 + gc);
      acc[0] += alpha * __uint_as_float(u.x << 16);
      acc[1] += alpha * __uint_as_float(u.x & 0xFFFF0000u);
      acc[2] += alpha * __uint_as_float(u.y << 16);
      acc[3] += alpha * __uint_as_float(u.y & 0xFFFF0000u);
    }
  }

  // bias + relu; layer-2 logit partials; pack h to LDS (bf16)
  const float4 bb = *(const float4*)(b1f + gc);
  float h0 = acc[0] + bb.x, h1 = acc[1] + bb.y;
  float h2 = acc[2] + bb.z, h3 = acc[3] + bb.w;
  h0 = h0 > 0.f ? h0 : 0.f; h1 = h1 > 0.f ? h1 : 0.f;
  h2 = h2 > 0.f ? h2 : 0.f; h3 = h3 > 0.f ? h3 : 0.f;
  const float4 vs = *(const float4*)(v2s + gc);
  const float4 vd = *(const float4*)(v2d + gc);
  float ps = h0 * vs.x + h1 * vs.y + h2 * vs.z + h3 * vs.w;
  float pd = h0 * vd.x + h1 * vd.y + h2 * vd.z + h3 * vd.w;
#pragma unroll
  for (int off = 1; off <= 32; off <<= 1) {
    ps += __shfl_xor(ps, off);
    pd += __shfl_xor(pd, off);
  }
  unsigned int p0 = (unsigned int)f2bf(h0) | ((unsigned int)f2bf(h1) << 16);
  unsigned int p1 = (unsigned int)f2bf(h2) | ((unsigned int)f2bf(h3) << 16);
  *(uint2*)&hb[wid][gc] = make_uint2(p0, p1);
  if (valid && lane == 0) {
    A2[(size_t)n * 2] = ps;
    A2[(size_t)n * 2 + 1] = pd;
  }
  __syncthreads();
  // block MFMA: wave wid computes 16-col tile [wid*16, wid*16+16) of
  // xs2 = h(4x256) @ W2s(256x64). A rows 4..15 are duplicates (discarded).
  const int m16 = lane & 15, quad = lane >> 4;
  floatx4 c2 = {0.f, 0.f, 0.f, 0.f};
  const unsigned short* arow = &hb[m16 & 3][0];
  const unsigned short* bcol = W2sT + (size_t)(wid * 16 + m16) * 256;
#pragma unroll
  for (int ks = 0; ks < 8; ++ks) {
    short8 afr = *(const short8*)(arow + ks * 32 + quad * 8);
    short8 bfr = *(const short8*)(bcol + ks * 32 + quad * 8);
    c2 = __builtin_amdgcn_mfma_f32_16x16x32_bf16(afr, bfr, c2, 0, 0, 0);
  }
  // C/D: col = m16 (within tile), row = quad*4 + r; rows 0..3 = block's nodes
  if (quad == 0) {
#pragma unroll
    for (int r = 0; r < 4; ++r) {
      int node = blockIdx.x * 4 + r;
      if (node < N) xs2[(size_t)node * 64 + wid * 16 + m16] = f2bf(c2[r]);
    }
  }
}

// layer-2 aggregation, one wave per node. FLOAT32 output.
__global__ __launch_bounds__(256) void node2(const int* __restrict__ rowst,
    const int* __restrict__ deg, const int* __restrict__ srcS,
    const float* __restrict__ A2, const unsigned short* __restrict__ xs2,
    const float* __restrict__ b2f, float* __restrict__ out, int N) {
  __shared__ int   s_sh[4][64];
  __shared__ float al_sh[4][64];
  const int lane = threadIdx.x & 63;
  const int wid = threadIdx.x >> 6;
  const int n = blockIdx.x * 4 + wid;
  if (n >= N) return;  // wave-uniform
  const int st = rowst[n], dn = deg[n];
  const float ad = A2[(size_t)n * 2 + 1];
  float acc = 0.f;
  if (dn <= 64) {
    int s = 0; float v = NEG_INF;
    if (lane < dn) {
      s = srcS[st + lane];
      v = A2[(size_t)s * 2] + ad;
      v = v > 0.f ? v : 0.2f * v;
    }
    float m = v;
#pragma unroll
    for (int off = 32; off; off >>= 1) m = fmaxf(m, __shfl_xor(m, off));
    float e = (lane < dn) ? __expf(v - m) : 0.f;
    float l = e;
#pragma unroll
    for (int off = 32; off; off >>= 1) l += __shfl_xor(l, off);
    if (lane < dn) { s_sh[wid][lane] = s; al_sh[wid][lane] = e / l; }
    int j = 0;
    for (; j + 4 <= dn; j += 4) {
      int s0 = s_sh[wid][j], s1 = s_sh[wid][j + 1];
      int s2 = s_sh[wid][j + 2], s3 = s_sh[wid][j + 3];
      float a0 = al_sh[wid][j],     a1 = al_sh[wid][j + 1];
      float a2 = al_sh[wid][j + 2], a3 = al_sh[wid][j + 3];
      float x0 = bf2f(xs2[(size_t)s0 * 64 + lane]);
      float x1 = bf2f(xs2[(size_t)s1 * 64 + lane]);
      float x2 = bf2f(xs2[(size_t)s2 * 64 + lane]);
      float x3 = bf2f(xs2[(size_t)s3 * 64 + lane]);
      acc += a0 * x0 + a1 * x1 + a2 * x2 + a3 * x3;
    }
    for (; j < dn; ++j)
      acc += al_sh[wid][j] * bf2f(xs2[(size_t)s_sh[wid][j] * 64 + lane]);
  } else {
    float m = NEG_INF;
    for (int j = lane; j < dn; j += 64) {
      int s = srcS[st + j];
      float v = A2[(size_t)s * 2] + ad;
      v = v > 0.f ? v : 0.2f * v;
      m = fmaxf(m, v);
    }
#pragma unroll
    for (int off = 32; off; off >>= 1) m = fmaxf(m, __shfl_xor(m, off));
    float l = 0.f;
    for (int j = lane; j < dn; j += 64) {
      int s = srcS[st + j];
      float v = A2[(size_t)s * 2] + ad;
      v = v > 0.f ? v : 0.2f * v;
      l += __expf(v - m);
    }
#pragma unroll
    for (int off = 32; off; off >>= 1) l += __shfl_xor(l, off);
    float inv = 1.0f / l;
    for (int j = 0; j < dn; ++j) {
      int s = srcS[st + j];
      float v = A2[(size_t)s * 2] + ad;
      v = v > 0.f ? v : 0.2f * v;
      acc += __expf(v - m) * inv * bf2f(xs2[(size_t)s * 64 + lane]);
    }
  }
  out[(size_t)n * 64 + lane] = acc + b2f[lane];
}

extern "C" void kernel_launch(void* const* d_in, const int* in_sizes, int n_in,
                              void* d_out, int out_size, void* d_ws, size_t ws_size,
                              hipStream_t stream) {
  const int F = 128, HC1 = 256, C2 = 64;
  const int N  = in_sizes[0] / F;
  const int E  = in_sizes[1] / 2;
  const int EP = E + N;
  (void)n_in;

  char* w = (char*)d_ws;
  size_t off = 0;
  auto alloc = [&](size_t bytes) -> char* {
    char* p = w + off;
    off = (off + bytes + 255) & ~(size_t)255;
    return p;
  };
  int* flags  = (int*)alloc(256);
  int* srcI   = (int*)alloc((size_t)EP * 4);
  int* dstI   = (int*)alloc((size_t)EP * 4);       // overlaid by A1 later
  int* degcur = (int*)alloc((size_t)2 * N * 4);    // zeroed
  int* deg    = degcur;
  int* cursor = degcur + N;
  int* rowst  = (int*)alloc((size_t)N * 4);
  int* bsum   = (int*)alloc(1024);
  unsigned short* W1c   = (unsigned short*)alloc((size_t)F * HC1 * 2);
  unsigned short* W1ext = (unsigned short*)alloc(128 * 16 * 2);
  unsigned short* W2sT  = (unsigned short*)alloc((size_t)HC1 * C2 * 2);
  float* v2s  = (float*)alloc(256 * 4);
  float* v2d  = (float*)alloc(256 * 4);
  float* b1f  = (float*)alloc(256 * 4);
  float* b2f  = (float*)alloc(64 * 4);
  int*   srcS = (int*)alloc((size_t)EP * 4);
  unsigned short* xs1 = (unsigned short*)alloc((size_t)N * HC1 * 2);
  unsigned short* xs2 = (unsigned short*)alloc((size_t)N * C2 * 2);
  float* A2 = (float*)alloc((size_t)N * 2 * 4);
  float* A1 = (float*)dstI;  // overlay after fill_srcS (1.6MB <= 1.8MB)
  const size_t need = off;   // ~39 MB

  if (ws_size < need) {  // canary: report ws MB via output
    fill_out_kernel<<<cdiv(out_size, 256), 256, 0, stream>>>(
        (float*)d_out, out_size, 131072.0f + 1024.0f * (float)(ws_size >> 20));
    return;
  }

  hipMemsetAsync(degcur, 0, (size_t)2 * N * 4, stream);
  detect_kernel<<<1, 256, 0, stream>>>((const unsigned short*)d_in[0],
                                       (const unsigned int*)d_in[1], flags);
  prep_kernel<<<195, 256, 0, stream>>>(d_in[2], d_in[3], d_in[4], d_in[5],
                                       d_in[7], d_in[8], d_in[9], d_in[10],
                                       d_in[6], d_in[11], flags,
                                       W1c, W2sT, W1ext, v2s, v2d, b1f, b2f);
  canon_edges_deg<<<cdiv(EP, 256), 256, 0, stream>>>(d_in[1], E, EP, N, flags,
                                                     srcI, dstI, deg);
  const int nb = cdiv(N, 256);
  scan1<<<nb, 256, 0, stream>>>(deg, N, rowst, bsum);
  scan2<<<1, 256, 0, stream>>>(bsum, nb);
  scan3<<<nb, 256, 0, stream>>>(rowst, deg, bsum, N);
  fill_srcS<<<cdiv(EP, 256), 256, 0, stream>>>(srcI, dstI, EP, rowst, cursor, srcS);

  gemm_full<<<cdiv(N, 64), 256, 0, stream>>>(d_in[0], flags, W1c, W1ext, xs1, A1, N);
  node1_merged<<<cdiv(N, 4), 256, 0, stream>>>(rowst, deg, srcS, A1, xs1,
                                               b1f, W2sT, v2s, v2d, xs2, A2, N);
  node2<<<cdiv(N, 4), 256, 0, stream>>>(rowst, deg, srcS, A2, xs2, b2f,
                                        (float*)d_out, N);
}

// Round 10
// 340.330 us; speedup vs baseline: 4.1365x; 1.0217x over previous
//
#include <hip/hip_runtime.h>

// ---------------------------------------------------------------------------
// GAT 2-layer forward (N=50k, F=128, L1: H=4 x 64, L2: 1 x 64), MI355X.
// Round 10: (1) gemm_full C-stores coalesced via LDS repack (was 25.6MB of
// scalar 2B stores); (2) dispatches 11->8 (detect+memset folded into prep,
// scan2 folded into scan3); (3) hb padded [4][272] to kill the 4.8M LDS bank
// conflicts in node1's MFMA epilogue (512B rows aliased 4-way).
// ---------------------------------------------------------------------------

static inline int cdiv(int a, int b) { return (a + b - 1) / b; }

typedef __attribute__((ext_vector_type(8))) short short8;
typedef __attribute__((ext_vector_type(4))) float floatx4;

__device__ __forceinline__ float bf2f(unsigned short u) {
  return __uint_as_float(((unsigned int)u) << 16);
}
__device__ __forceinline__ unsigned short f2bf(float f) {  // RNE
  unsigned int u = __float_as_uint(f);
  unsigned int r = (u + 0x7FFFu + ((u >> 16) & 1u)) >> 16;
  return (unsigned short)r;
}
__device__ __forceinline__ float ldv(const void* p, int i, int bf) {
  return bf ? bf2f(((const unsigned short*)p)[i]) : ((const float*)p)[i];
}
#define NEG_INF (-__builtin_inff())

__global__ void fill_out_kernel(float* __restrict__ out, int n, float val) {
  int t = blockIdx.x * blockDim.x + threadIdx.x;
  if (t < n) out[t] = val;
}

// per-block bf16-vs-f32 probe on x (deterministic; all blocks agree)
__device__ int block_bf_flag(const unsigned short* xu) {
  __shared__ int cc;
  if (threadIdx.x == 0) cc = 0;
  __syncthreads();
  int l = 0;
  for (int i = threadIdx.x; i < 1024; i += 256) {
    int e = (xu[2 * i] >> 7) & 0xFF;
    if (e >= 100 && e <= 141) l++;
  }
  atomicAdd(&cc, l);
  __syncthreads();
  return cc > 512 ? 1 : 0;
}

// Consolidated prep. Blocks:
//  [0,128)    : W1c = bf16(W1s)           (block 0 also publishes flags)
//  [128,192)  : W2sT transpose
//  192        : W1ext fused att1 vectors (cols 8..15 zeroed)
//  193        : v2s/v2d fused att2 vectors
//  194        : b1f/b2f
//  [195, ...) : zero degcur (2N ints)
__global__ void prep_kernel(const unsigned short* __restrict__ xu,
                            const unsigned int* __restrict__ eu,
                            const void* __restrict__ W1s, const void* __restrict__ W1d,
                            const void* __restrict__ att1s, const void* __restrict__ att1d,
                            const void* __restrict__ W2s, const void* __restrict__ W2d,
                            const void* __restrict__ att2s, const void* __restrict__ att2d,
                            const void* __restrict__ b1, const void* __restrict__ b2,
                            int* __restrict__ flags,
                            unsigned short* __restrict__ W1c,
                            unsigned short* __restrict__ W2sT,
                            unsigned short* __restrict__ W1ext,
                            float* __restrict__ v2s, float* __restrict__ v2d,
                            float* __restrict__ b1f, float* __restrict__ b2f,
                            int* __restrict__ degcur, int zero_n) {
  const int b = blockIdx.x, t = threadIdx.x;
  if (b >= 195) {                         // zero region
    int i = (b - 195) * 256 + t;
    if (i < zero_n) degcur[i] = 0;
    return;
  }
  const int bf = block_bf_flag(xu);
  if (b == 0 && t < 64) {                 // publish flags (edge probe by wave 0)
    __shared__ int ce;
    if (t == 0) ce = 0;
    __syncthreads();
    int l1 = 0;
    for (int i = t; i < 1024; i += 64)
      if (eu[2 * i + 1] == 0u) l1++;
    atomicAdd(&ce, l1);
    __syncthreads();
    if (t == 0) { flags[0] = bf; flags[1] = (ce > 512) ? 1 : 0; }
  }
  if (b < 128) {
    int i = b * 256 + t;
    W1c[i] = f2bf(ldv(W1s, i, bf));
  } else if (b < 192) {
    int i = (b - 128) * 256 + t;
    int k = i >> 6, col = i & 63;
    W2sT[col * 256 + k] = f2bf(ldv(W2s, i, bf));
  } else if (b == 192) {
    for (int r = 0; r < 4; ++r) {
      int idx = r * 256 + t;
      int k = idx >> 3, q = idx & 7;
      int h = q & 3;
      const void* W = (q < 4) ? W1s : W1d;
      const void* A = (q < 4) ? att1s : att1d;
      float s = 0.f;
      for (int c = 0; c < 64; ++c)
        s += ldv(W, k * 256 + h * 64 + c, bf) * ldv(A, h * 64 + c, bf);
      W1ext[k * 16 + q] = f2bf(s);
      W1ext[k * 16 + 8 + q] = 0;
    }
  } else if (b == 193) {
    for (int r = 0; r < 2; ++r) {
      int idx = r * 256 + t;
      int k = idx & 255;
      const void* W = (idx < 256) ? W2s : W2d;
      const void* A = (idx < 256) ? att2s : att2d;
      float s = 0.f;
      for (int c = 0; c < 64; ++c) s += ldv(W, k * 64 + c, bf) * ldv(A, c, bf);
      if (idx < 256) v2s[k] = s; else v2d[k] = s;
    }
  } else {
    if (t < 256) b1f[t] = ldv(b1, t, bf);
    if (t < 64)  b2f[t] = ldv(b2, t, bf);
  }
}

__global__ void canon_edges_deg(const void* __restrict__ ei, int E, int EP, int Nn,
                                const int* __restrict__ flags,
                                int* __restrict__ srcI, int* __restrict__ dstI,
                                int* __restrict__ deg) {
  int t = blockIdx.x * blockDim.x + threadIdx.x;
  if (t >= EP) return;
  int s, d;
  if (t < E) {
    if (flags[1]) {
      const unsigned int* p = (const unsigned int*)ei;
      s = (int)p[2 * (size_t)t];
      d = (int)p[2 * ((size_t)E + t)];
    } else {
      const int* p = (const int*)ei;
      s = p[t]; d = p[E + t];
    }
  } else { s = t - E; d = s; }
  if ((unsigned)s >= (unsigned)Nn) s = 0;
  if ((unsigned)d >= (unsigned)Nn) d = 0;
  srcI[t] = s; dstI[t] = d;
  atomicAdd(&deg[d], 1);
}

__global__ void scan1(const int* __restrict__ deg, int N,
                      int* __restrict__ incl, int* __restrict__ bsum) {
  __shared__ int s[256];
  int i = blockIdx.x * 256 + threadIdx.x;
  int v = (i < N) ? deg[i] : 0;
  s[threadIdx.x] = v;
  __syncthreads();
  for (int off = 1; off < 256; off <<= 1) {
    int add = (threadIdx.x >= off) ? s[threadIdx.x - off] : 0;
    __syncthreads();
    s[threadIdx.x] += add;
    __syncthreads();
  }
  if (i < N) incl[i] = s[threadIdx.x];
  if (threadIdx.x == 255) bsum[blockIdx.x] = s[255];
}

// finalize row starts; block computes its own exclusive bsum prefix (nb<=256)
__global__ void scan3(int* __restrict__ incl, const int* __restrict__ deg,
                      const int* __restrict__ bsum, int N, int nb) {
  __shared__ int s[256];
  const int t = threadIdx.x;
  s[t] = (t < blockIdx.x && t < nb) ? bsum[t] : 0;
  __syncthreads();
  for (int off = 128; off; off >>= 1) {
    if (t < off) s[t] += s[t + off];
    __syncthreads();
  }
  int pre = s[0];
  int i = blockIdx.x * 256 + t;
  if (i < N) incl[i] = incl[i] + pre - deg[i];
}

// CSR fill: materialize src node id per row slot
__global__ void fill_srcS(const int* __restrict__ srcI, const int* __restrict__ dstI,
                          int EP, const int* __restrict__ rowst,
                          int* __restrict__ cursor, int* __restrict__ srcS) {
  int t = blockIdx.x * blockDim.x + threadIdx.x;
  if (t >= EP) return;
  int d = dstI[t];
  int pos = atomicAdd(&cursor[d], 1);
  srcS[rowst[d] + pos] = srcI[t];
}

// ---- MFMA GEMM: xs1 = x @ W1 (256 cols) + A1 = x @ v1. Coalesced stores via
// LDS repack (pitch 136 ushorts -> rows spread 8 banks; 16B-aligned b128).
__global__ __launch_bounds__(256) void gemm_full(
    const void* __restrict__ X, const int* __restrict__ flags,
    const unsigned short* __restrict__ W1c, const unsigned short* __restrict__ W1ext,
    unsigned short* __restrict__ xs1, float* __restrict__ A1, int M) {
  __shared__ unsigned short Wlds[9 * 16 * 136];      // also reused as C buffer
  const int t = threadIdx.x;
  const int lane = t & 63, wid = t >> 6;
  const int quad = lane >> 4, m16 = lane & 15;
  const int r0b = blockIdx.x * 64;
  const int r0 = r0b + wid * 16;
  const int arow = min(r0 + m16, M - 1);
  short8 af[4];
  if (flags[0]) {
    const uint4* Xr = (const uint4*)((const unsigned int*)X + (size_t)arow * 64);
#pragma unroll
    for (int ks = 0; ks < 4; ++ks)
      af[ks] = __builtin_bit_cast(short8, Xr[ks * 4 + quad]);
  } else {
    const float* Xr = (const float*)X + (size_t)arow * 128;
#pragma unroll
    for (int ks = 0; ks < 4; ++ks) {
      short8 v;
#pragma unroll
      for (int j = 0; j < 8; ++j) v[j] = (short)f2bf(Xr[ks * 32 + quad * 8 + j]);
      af[ks] = v;
    }
  }
  floatx4 accs[9];

  // ===== phase 0: cols 0..127 (+ A1 tile) =====
  if (t < 144) {
    for (int k0 = 0; k0 < 128; k0 += 4) {
      unsigned int u0, u1;
      if (t < 128) {
        const unsigned short* p = W1c + (size_t)k0 * 256 + t;
        u0 = (unsigned int)p[0] | ((unsigned int)p[256] << 16);
        u1 = (unsigned int)p[512] | ((unsigned int)p[768] << 16);
      } else {
        const unsigned short* p = W1ext + (size_t)k0 * 16 + (t - 128);
        u0 = (unsigned int)p[0] | ((unsigned int)p[16] << 16);
        u1 = (unsigned int)p[32] | ((unsigned int)p[48] << 16);
      }
      *(uint2*)&Wlds[t * 136 + k0] = make_uint2(u0, u1);
    }
  }
  __syncthreads();
#pragma unroll
  for (int ct = 0; ct < 9; ++ct) {
    floatx4 acc = {0.f, 0.f, 0.f, 0.f};
    const unsigned short* wl = &Wlds[(ct * 16 + m16) * 136];
#pragma unroll
    for (int ks = 0; ks < 4; ++ks) {
      short8 bfv = *(const short8*)(wl + ks * 32 + quad * 8);
      acc = __builtin_amdgcn_mfma_f32_16x16x32_bf16(af[ks], bfv, acc, 0, 0, 0);
    }
    accs[ct] = acc;
  }
  __syncthreads();                        // all waves done reading Wlds
  if (m16 < 8) {                          // A1 tile (direct store, small)
#pragma unroll
    for (int r = 0; r < 4; ++r) {
      int row = r0 + quad * 4 + r;
      if (row < M) A1[(size_t)row * 8 + m16] = accs[8][r];
    }
  }
#pragma unroll
  for (int ct = 0; ct < 8; ++ct)          // repack C into LDS
#pragma unroll
    for (int r = 0; r < 4; ++r)
      Wlds[(wid * 16 + quad * 4 + r) * 136 + ct * 16 + m16] = f2bf(accs[ct][r]);
  __syncthreads();
#pragma unroll
  for (int it = 0; it < 4; ++it) {        // coalesced dwordx4 stores
    int lrow = it * 16 + (t >> 4);
    int grow = r0b + lrow;
    if (grow < M) {
      uint4 v = *(const uint4*)&Wlds[lrow * 136 + (t & 15) * 8];
      *(uint4*)(xs1 + (size_t)grow * 256 + (t & 15) * 8) = v;
    }
  }
  __syncthreads();

  // ===== phase 1: cols 128..255 =====
  if (t < 128) {
    for (int k0 = 0; k0 < 128; k0 += 4) {
      const unsigned short* p = W1c + (size_t)k0 * 256 + 128 + t;
      unsigned int u0 = (unsigned int)p[0] | ((unsigned int)p[256] << 16);
      unsigned int u1 = (unsigned int)p[512] | ((unsigned int)p[768] << 16);
      *(uint2*)&Wlds[t * 136 + k0] = make_uint2(u0, u1);
    }
  }
  __syncthreads();
#pragma unroll
  for (int ct = 0; ct < 8; ++ct) {
    floatx4 acc = {0.f, 0.f, 0.f, 0.f};
    const unsigned short* wl = &Wlds[(ct * 16 + m16) * 136];
#pragma unroll
    for (int ks = 0; ks < 4; ++ks) {
      short8 bfv = *(const short8*)(wl + ks * 32 + quad * 8);
      acc = __builtin_amdgcn_mfma_f32_16x16x32_bf16(af[ks], bfv, acc, 0, 0, 0);
    }
    accs[ct] = acc;
  }
  __syncthreads();
#pragma unroll
  for (int ct = 0; ct < 8; ++ct)
#pragma unroll
    for (int r = 0; r < 4; ++r)
      Wlds[(wid * 16 + quad * 4 + r) * 136 + ct * 16 + m16] = f2bf(accs[ct][r]);
  __syncthreads();
#pragma unroll
  for (int it = 0; it < 4; ++it) {
    int lrow = it * 16 + (t >> 4);
    int grow = r0b + lrow;
    if (grow < M) {
      uint4 v = *(const uint4*)&Wlds[lrow * 136 + (t & 15) * 8];
      *(uint4*)(xs1 + (size_t)grow * 256 + 128 + (t & 15) * 8) = v;
    }
  }
}

// ---- node1: softmax + gather (4 heads), block-MFMA epilogue for xs2=h@W2s.
__global__ __launch_bounds__(256) void node1_merged(
    const int* __restrict__ rowst, const int* __restrict__ deg,
    const int* __restrict__ srcS,
    const float* __restrict__ A1, const unsigned short* __restrict__ xs1,
    const float* __restrict__ b1f, const unsigned short* __restrict__ W2sT,
    const float* __restrict__ v2s, const float* __restrict__ v2d,
    unsigned short* __restrict__ xs2, float* __restrict__ A2, int N) {
  __shared__ unsigned short hb[4][272];   // 272-pitch: rows on disjoint banks
  __shared__ int   s_sh[4][64];
  __shared__ float al_sh[4][64][4];
  const int lane = threadIdx.x & 63;
  const int wid = threadIdx.x >> 6;
  const int nraw = blockIdx.x * 4 + wid;
  const bool valid = nraw < N;
  const int n = valid ? nraw : (N - 1);
  const int st = rowst[n], dn = deg[n];
  const float4 ad4 = *(const float4*)(A1 + (size_t)n * 8 + 4);
  const float ad[4] = {ad4.x, ad4.y, ad4.z, ad4.w};
  const int gc = 4 * lane;
  const int hL = lane >> 4;
  float acc[4] = {0.f, 0.f, 0.f, 0.f};

  if (dn <= 64) {
    int s = 0;
    float v[4] = {NEG_INF, NEG_INF, NEG_INF, NEG_INF};
    if (lane < dn) {
      s = srcS[st + lane];
      const float4 as4 = *(const float4*)(A1 + (size_t)s * 8);
      const float as[4] = {as4.x, as4.y, as4.z, as4.w};
#pragma unroll
      for (int h = 0; h < 4; ++h) {
        float x = as[h] + ad[h];
        v[h] = x > 0.f ? x : 0.2f * x;
      }
    }
    float m[4], l[4];
#pragma unroll
    for (int h = 0; h < 4; ++h) {
      m[h] = v[h];
#pragma unroll
      for (int off = 32; off; off >>= 1) m[h] = fmaxf(m[h], __shfl_xor(m[h], off));
      float e = (lane < dn) ? __expf(v[h] - m[h]) : 0.f;
      l[h] = e;
#pragma unroll
      for (int off = 32; off; off >>= 1) l[h] += __shfl_xor(l[h], off);
      v[h] = e;
    }
    if (lane < dn) {
      s_sh[wid][lane] = s;
      float4 al = {v[0] / l[0], v[1] / l[1], v[2] / l[2], v[3] / l[3]};
      *(float4*)&al_sh[wid][lane][0] = al;
    }
    int j = 0;
    for (; j + 4 <= dn; j += 4) {
      int s0 = s_sh[wid][j], s1 = s_sh[wid][j + 1];
      int s2 = s_sh[wid][j + 2], s3 = s_sh[wid][j + 3];
      float a0 = al_sh[wid][j][hL],     a1 = al_sh[wid][j + 1][hL];
      float a2 = al_sh[wid][j + 2][hL], a3 = al_sh[wid][j + 3][hL];
      uint2 u0 = *(const uint2*)(xs1 + (size_t)s0 * 256 + gc);
      uint2 u1 = *(const uint2*)(xs1 + (size_t)s1 * 256 + gc);
      uint2 u2 = *(const uint2*)(xs1 + (size_t)s2 * 256 + gc);
      uint2 u3 = *(const uint2*)(xs1 + (size_t)s3 * 256 + gc);
      acc[0] += a0 * __uint_as_float(u0.x << 16);
      acc[1] += a0 * __uint_as_float(u0.x & 0xFFFF0000u);
      acc[2] += a0 * __uint_as_float(u0.y << 16);
      acc[3] += a0 * __uint_as_float(u0.y & 0xFFFF0000u);
      acc[0] += a1 * __uint_as_float(u1.x << 16);
      acc[1] += a1 * __uint_as_float(u1.x & 0xFFFF0000u);
      acc[2] += a1 * __uint_as_float(u1.y << 16);
      acc[3] += a1 * __uint_as_float(u1.y & 0xFFFF0000u);
      acc[0] += a2 * __uint_as_float(u2.x << 16);
      acc[1] += a2 * __uint_as_float(u2.x & 0xFFFF0000u);
      acc[2] += a2 * __uint_as_float(u2.y << 16);
      acc[3] += a2 * __uint_as_float(u2.y & 0xFFFF0000u);
      acc[0] += a3 * __uint_as_float(u3.x << 16);
      acc[1] += a3 * __uint_as_float(u3.x & 0xFFFF0000u);
      acc[2] += a3 * __uint_as_float(u3.y << 16);
      acc[3] += a3 * __uint_as_float(u3.y & 0xFFFF0000u);
    }
    for (; j < dn; ++j) {
      int s0 = s_sh[wid][j];
      float a0 = al_sh[wid][j][hL];
      uint2 u0 = *(const uint2*)(xs1 + (size_t)s0 * 256 + gc);
      acc[0] += a0 * __uint_as_float(u0.x << 16);
      acc[1] += a0 * __uint_as_float(u0.x & 0xFFFF0000u);
      acc[2] += a0 * __uint_as_float(u0.y << 16);
      acc[3] += a0 * __uint_as_float(u0.y & 0xFFFF0000u);
    }
  } else {
    float m[4] = {NEG_INF, NEG_INF, NEG_INF, NEG_INF};
    for (int j = lane; j < dn; j += 64) {
      int s = srcS[st + j];
      const float4 as4 = *(const float4*)(A1 + (size_t)s * 8);
      const float as[4] = {as4.x, as4.y, as4.z, as4.w};
#pragma unroll
      for (int h = 0; h < 4; ++h) {
        float x = as[h] + ad[h];
        x = x > 0.f ? x : 0.2f * x;
        m[h] = fmaxf(m[h], x);
      }
    }
#pragma unroll
    for (int h = 0; h < 4; ++h)
#pragma unroll
      for (int off = 32; off; off >>= 1) m[h] = fmaxf(m[h], __shfl_xor(m[h], off));
    float l[4] = {0.f, 0.f, 0.f, 0.f};
    for (int j = lane; j < dn; j += 64) {
      int s = srcS[st + j];
      const float4 as4 = *(const float4*)(A1 + (size_t)s * 8);
      const float as[4] = {as4.x, as4.y, as4.z, as4.w};
#pragma unroll
      for (int h = 0; h < 4; ++h) {
        float x = as[h] + ad[h];
        x = x > 0.f ? x : 0.2f * x;
        l[h] += __expf(x - m[h]);
      }
    }
#pragma unroll
    for (int h = 0; h < 4; ++h)
#pragma unroll
      for (int off = 32; off; off >>= 1) l[h] += __shfl_xor(l[h], off);
    const float mh = m[hL], inv = 1.0f / l[hL], adh = ad[hL];
    for (int j = 0; j < dn; ++j) {
      int s = srcS[st + j];
      float x = A1[(size_t)s * 8 + hL] + adh;
      x = x > 0.f ? x : 0.2f * x;
      float alpha = __expf(x - mh) * inv;
      uint2 u = *(const uint2*)(xs1 + (size_t)s * 256 + gc);
      acc[0] += alpha * __uint_as_float(u.x << 16);
      acc[1] += alpha * __uint_as_float(u.x & 0xFFFF0000u);
      acc[2] += alpha * __uint_as_float(u.y << 16);
      acc[3] += alpha * __uint_as_float(u.y & 0xFFFF0000u);
    }
  }

  const float4 bb = *(const float4*)(b1f + gc);
  float h0 = acc[0] + bb.x, h1 = acc[1] + bb.y;
  float h2 = acc[2] + bb.z, h3 = acc[3] + bb.w;
  h0 = h0 > 0.f ? h0 : 0.f; h1 = h1 > 0.f ? h1 : 0.f;
  h2 = h2 > 0.f ? h2 : 0.f; h3 = h3 > 0.f ? h3 : 0.f;
  const float4 vs = *(const float4*)(v2s + gc);
  const float4 vd = *(const float4*)(v2d + gc);
  float ps = h0 * vs.x + h1 * vs.y + h2 * vs.z + h3 * vs.w;
  float pd = h0 * vd.x + h1 * vd.y + h2 * vd.z + h3 * vd.w;
#pragma unroll
  for (int off = 1; off <= 32; off <<= 1) {
    ps += __shfl_xor(ps, off);
    pd += __shfl_xor(pd, off);
  }
  unsigned int p0 = (unsigned int)f2bf(h0) | ((unsigned int)f2bf(h1) << 16);
  unsigned int p1 = (unsigned int)f2bf(h2) | ((unsigned int)f2bf(h3) << 16);
  *(uint2*)&hb[wid][gc] = make_uint2(p0, p1);
  if (valid && lane == 0) {
    A2[(size_t)n * 2] = ps;
    A2[(size_t)n * 2 + 1] = pd;
  }
  __syncthreads();
  // block MFMA: wave wid -> 16-col tile of xs2 = h(4x256) @ W2s(256x64)
  const int m16 = lane & 15, quad = lane >> 4;
  floatx4 c2 = {0.f, 0.f, 0.f, 0.f};
  const unsigned short* arow = &hb[m16 & 3][0];
  const unsigned short* bcol = W2sT + (size_t)(wid * 16 + m16) * 256;
#pragma unroll
  for (int ks = 0; ks < 8; ++ks) {
    short8 afr = *(const short8*)(arow + ks * 32 + quad * 8);
    short8 bfr = *(const short8*)(bcol + ks * 32 + quad * 8);
    c2 = __builtin_amdgcn_mfma_f32_16x16x32_bf16(afr, bfr, c2, 0, 0, 0);
  }
  if (quad == 0) {
#pragma unroll
    for (int r = 0; r < 4; ++r) {
      int node = blockIdx.x * 4 + r;
      if (node < N) xs2[(size_t)node * 64 + wid * 16 + m16] = f2bf(c2[r]);
    }
  }
}

// layer-2 aggregation, one wave per node. FLOAT32 output.
__global__ __launch_bounds__(256) void node2(const int* __restrict__ rowst,
    const int* __restrict__ deg, const int* __restrict__ srcS,
    const float* __restrict__ A2, const unsigned short* __restrict__ xs2,
    const float* __restrict__ b2f, float* __restrict__ out, int N) {
  __shared__ int   s_sh[4][64];
  __shared__ float al_sh[4][64];
  const int lane = threadIdx.x & 63;
  const int wid = threadIdx.x >> 6;
  const int n = blockIdx.x * 4 + wid;
  if (n >= N) return;  // wave-uniform
  const int st = rowst[n], dn = deg[n];
  const float ad = A2[(size_t)n * 2 + 1];
  float acc = 0.f;
  if (dn <= 64) {
    int s = 0; float v = NEG_INF;
    if (lane < dn) {
      s = srcS[st + lane];
      v = A2[(size_t)s * 2] + ad;
      v = v > 0.f ? v : 0.2f * v;
    }
    float m = v;
#pragma unroll
    for (int off = 32; off; off >>= 1) m = fmaxf(m, __shfl_xor(m, off));
    float e = (lane < dn) ? __expf(v - m) : 0.f;
    float l = e;
#pragma unroll
    for (int off = 32; off; off >>= 1) l += __shfl_xor(l, off);
    if (lane < dn) { s_sh[wid][lane] = s; al_sh[wid][lane] = e / l; }
    int j = 0;
    for (; j + 4 <= dn; j += 4) {
      int s0 = s_sh[wid][j], s1 = s_sh[wid][j + 1];
      int s2 = s_sh[wid][j + 2], s3 = s_sh[wid][j + 3];
      float a0 = al_sh[wid][j],     a1 = al_sh[wid][j + 1];
      float a2 = al_sh[wid][j + 2], a3 = al_sh[wid][j + 3];
      float x0 = bf2f(xs2[(size_t)s0 * 64 + lane]);
      float x1 = bf2f(xs2[(size_t)s1 * 64 + lane]);
      float x2 = bf2f(xs2[(size_t)s2 * 64 + lane]);
      float x3 = bf2f(xs2[(size_t)s3 * 64 + lane]);
      acc += a0 * x0 + a1 * x1 + a2 * x2 + a3 * x3;
    }
    for (; j < dn; ++j)
      acc += al_sh[wid][j] * bf2f(xs2[(size_t)s_sh[wid][j] * 64 + lane]);
  } else {
    float m = NEG_INF;
    for (int j = lane; j < dn; j += 64) {
      int s = srcS[st + j];
      float v = A2[(size_t)s * 2] + ad;
      v = v > 0.f ? v : 0.2f * v;
      m = fmaxf(m, v);
    }
#pragma unroll
    for (int off = 32; off; off >>= 1) m = fmaxf(m, __shfl_xor(m, off));
    float l = 0.f;
    for (int j = lane; j < dn; j += 64) {
      int s = srcS[st + j];
      float v = A2[(size_t)s * 2] + ad;
      v = v > 0.f ? v : 0.2f * v;
      l += __expf(v - m);
    }
#pragma unroll
    for (int off = 32; off; off >>= 1) l += __shfl_xor(l, off);
    float inv = 1.0f / l;
    for (int j = 0; j < dn; ++j) {
      int s = srcS[st + j];
      float v = A2[(size_t)s * 2] + ad;
      v = v > 0.f ? v : 0.2f * v;
      acc += __expf(v - m) * inv * bf2f(xs2[(size_t)s * 64 + lane]);
    }
  }
  out[(size_t)n * 64 + lane] = acc + b2f[lane];
}

extern "C" void kernel_launch(void* const* d_in, const int* in_sizes, int n_in,
                              void* d_out, int out_size, void* d_ws, size_t ws_size,
                              hipStream_t stream) {
  const int F = 128, HC1 = 256, C2 = 64;
  const int N  = in_sizes[0] / F;
  const int E  = in_sizes[1] / 2;
  const int EP = E + N;
  (void)n_in;

  char* w = (char*)d_ws;
  size_t off = 0;
  auto alloc = [&](size_t bytes) -> char* {
    char* p = w + off;
    off = (off + bytes + 255) & ~(size_t)255;
    return p;
  };
  int* flags  = (int*)alloc(256);
  int* srcI   = (int*)alloc((size_t)EP * 4);
  int* dstI   = (int*)alloc((size_t)EP * 4);       // overlaid by A1 later
  int* degcur = (int*)alloc((size_t)2 * N * 4);    // zeroed by prep
  int* deg    = degcur;
  int* cursor = degcur + N;
  int* rowst  = (int*)alloc((size_t)N * 4);
  int* bsum   = (int*)alloc(1024);
  unsigned short* W1c   = (unsigned short*)alloc((size_t)F * HC1 * 2);
  unsigned short* W1ext = (unsigned short*)alloc(128 * 16 * 2);
  unsigned short* W2sT  = (unsigned short*)alloc((size_t)HC1 * C2 * 2);
  float* v2s  = (float*)alloc(256 * 4);
  float* v2d  = (float*)alloc(256 * 4);
  float* b1f  = (float*)alloc(256 * 4);
  float* b2f  = (float*)alloc(64 * 4);
  int*   srcS = (int*)alloc((size_t)EP * 4);
  unsigned short* xs1 = (unsigned short*)alloc((size_t)N * HC1 * 2);
  unsigned short* xs2 = (unsigned short*)alloc((size_t)N * C2 * 2);
  float* A2 = (float*)alloc((size_t)N * 2 * 4);
  float* A1 = (float*)dstI;  // overlay after fill_srcS (1.6MB <= 1.8MB)
  const size_t need = off;   // ~39 MB

  if (ws_size < need) {  // canary: report ws MB via output
    fill_out_kernel<<<cdiv(out_size, 256), 256, 0, stream>>>(
        (float*)d_out, out_size, 131072.0f + 1024.0f * (float)(ws_size >> 20));
    return;
  }

  const int zero_n = 2 * N;
  prep_kernel<<<195 + cdiv(zero_n, 256), 256, 0, stream>>>(
      (const unsigned short*)d_in[0], (const unsigned int*)d_in[1],
      d_in[2], d_in[3], d_in[4], d_in[5], d_in[7], d_in[8], d_in[9], d_in[10],
      d_in[6], d_in[11], flags, W1c, W2sT, W1ext, v2s, v2d, b1f, b2f,
      degcur, zero_n);
  canon_edges_deg<<<cdiv(EP, 256), 256, 0, stream>>>(d_in[1], E, EP, N, flags,
                                                     srcI, dstI, deg);
  const int nb = cdiv(N, 256);
  scan1<<<nb, 256, 0, stream>>>(deg, N, rowst, bsum);
  scan3<<<nb, 256, 0, stream>>>(rowst, deg, bsum, N, nb);
  fill_srcS<<<cdiv(EP, 256), 256, 0, stream>>>(srcI, dstI, EP, rowst, cursor, srcS);

  gemm_full<<<cdiv(N, 64), 256, 0, stream>>>(d_in[0], flags, W1c, W1ext, xs1, A1, N);
  node1_merged<<<cdiv(N, 4), 256, 0, stream>>>(rowst, deg, srcS, A1, xs1,
                                               b1f, W2sT, v2s, v2d, xs2, A2, N);
  node2<<<cdiv(N, 4), 256, 0, stream>>>(rowst, deg, srcS, A2, xs2, b2f,
                                        (float*)d_out, N);
}